// Round 1
// baseline (1487.781 us; speedup 1.0000x reference)
//
#include <hip/hip_runtime.h>

#define D_MODEL 1024
#define N_HEAD  16
#define D_K     64
#define BATCH   2
#define SEQ     2048
#define M_ROWS  (BATCH*SEQ)

// ---------------- GEMM: C = A @ W^T + bias ----------------
// A: MxK row-major, W: NxK row-major (so C = A @ W.T), C: MxN
constexpr int BM = 128, BN = 128, BK = 8;

__global__ __launch_bounds__(256)
void sgemm_nt_bias(const float* __restrict__ A, const float* __restrict__ W,
                   const float* __restrict__ bias, float* __restrict__ C,
                   int M, int N, int K)
{
    __shared__ float As[BK][BM];   // [k][m]
    __shared__ float Bs[BK][BN];   // [k][n]
    const int tid = threadIdx.x;
    const int bm = blockIdx.y * BM;
    const int bn = blockIdx.x * BN;
    // 8x8 micro-tile split 4+4 at +64 to keep LDS reads conflict-free
    const int rm = (tid >> 4) * 4;     // 0..60
    const int cn = (tid & 15) * 4;     // 0..60
    const int lr = tid >> 1;           // 0..127
    const int lc = (tid & 1) * 4;      // 0 or 4

    const float* Ap = A + (size_t)(bm + lr) * K + lc;
    const float* Wp = W + (size_t)(bn + lr) * K + lc;

    float acc[8][8];
#pragma unroll
    for (int i = 0; i < 8; ++i)
#pragma unroll
        for (int j = 0; j < 8; ++j) acc[i][j] = 0.f;

    // register prefetch (grid is 1 block/CU; hide global latency under compute)
    float4 av = *(const float4*)Ap;
    float4 wv = *(const float4*)Wp;

    for (int k0 = 0; k0 < K; k0 += BK) {
        As[lc+0][lr] = av.x; As[lc+1][lr] = av.y;
        As[lc+2][lr] = av.z; As[lc+3][lr] = av.w;
        Bs[lc+0][lr] = wv.x; Bs[lc+1][lr] = wv.y;
        Bs[lc+2][lr] = wv.z; Bs[lc+3][lr] = wv.w;
        __syncthreads();
        if (k0 + BK < K) {
            av = *(const float4*)(Ap + k0 + BK);
            wv = *(const float4*)(Wp + k0 + BK);
        }
#pragma unroll
        for (int k = 0; k < BK; ++k) {
            float a[8], b[8];
            *(float4*)(a+0) = *(const float4*)&As[k][rm];
            *(float4*)(a+4) = *(const float4*)&As[k][rm+64];
            *(float4*)(b+0) = *(const float4*)&Bs[k][cn];
            *(float4*)(b+4) = *(const float4*)&Bs[k][cn+64];
#pragma unroll
            for (int i = 0; i < 8; ++i)
#pragma unroll
                for (int j = 0; j < 8; ++j)
                    acc[i][j] = fmaf(a[i], b[j], acc[i][j]);
        }
        __syncthreads();
    }

#pragma unroll
    for (int i = 0; i < 8; ++i) {
        const int row = bm + ((i < 4) ? (rm + i) : (64 + rm + (i - 4)));
#pragma unroll
        for (int hh = 0; hh < 2; ++hh) {
            const int col = bn + ((hh == 0) ? cn : (64 + cn));
            float4 o;
            o.x = acc[i][hh*4+0] + bias[col+0];
            o.y = acc[i][hh*4+1] + bias[col+1];
            o.z = acc[i][hh*4+2] + bias[col+2];
            o.w = acc[i][hh*4+3] + bias[col+3];
            *(float4*)&C[(size_t)row * N + col] = o;
        }
    }
}

// ---------------- flash-style attention, fp32 ----------------
// one block = one (b,h) x 64 query rows; loop over 64-wide K/V tiles
constexpr int TKV = 64;
constexpr int PAD_LD = 68;   // 68*4B = 272B rows: keeps float4 alignment, spreads banks

__global__ __launch_bounds__(256)
void attn_fwd(const float* __restrict__ Qm, const float* __restrict__ Km,
              const float* __restrict__ Vm, const int* __restrict__ mask,
              float* __restrict__ ctx)
{
    __shared__ float Qst[D_K][64];      // [d][qrow]   (transposed)
    __shared__ float Kts[D_K][64];      // [d][kcol]   (transposed)
    __shared__ float Vs [TKV][PAD_LD];  // [kc][d]
    __shared__ float Pt [TKV][PAD_LD];  // [kc][qrow]  (P transposed)

    const int tid = threadIdx.x;
    const int tx = tid & 15;           // -> 4 k-cols / 4 d-cols
    const int ty = tid >> 4;           // -> 4 q-rows
    const int b  = blockIdx.y >> 4;
    const int h  = blockIdx.y & 15;
    const int q0 = blockIdx.x * 64;

    const size_t hbase = (size_t)b * SEQ * D_MODEL + (size_t)h * D_K;

    const int lr  = tid >> 2;          // load row 0..63
    const int ld0 = (tid & 3) * 16;    // load d-offset

    { // Q tile -> LDS transposed
        const float* p = Qm + hbase + (size_t)(q0 + lr) * D_MODEL + ld0;
#pragma unroll
        for (int jj = 0; jj < 4; ++jj) {
            float4 v4 = *(const float4*)(p + jj*4);
            Qst[ld0 + jj*4 + 0][lr] = v4.x;
            Qst[ld0 + jj*4 + 1][lr] = v4.y;
            Qst[ld0 + jj*4 + 2][lr] = v4.z;
            Qst[ld0 + jj*4 + 3][lr] = v4.w;
        }
    }

    float m_i[4], l_i[4], O[4][4];
#pragma unroll
    for (int i = 0; i < 4; ++i) {
        m_i[i] = -1e30f; l_i[i] = 0.f;
#pragma unroll
        for (int j = 0; j < 4; ++j) O[i][j] = 0.f;
    }

    // prefetch tile 0 (K, V, mask) into registers
    float4 kreg[4], vreg[4];
    int4 mreg[4];
    {
        const float* kp = Km + hbase + (size_t)lr * D_MODEL + ld0;
        const float* vp = Vm + hbase + (size_t)lr * D_MODEL + ld0;
#pragma unroll
        for (int jj = 0; jj < 4; ++jj) {
            kreg[jj] = *(const float4*)(kp + jj*4);
            vreg[jj] = *(const float4*)(vp + jj*4);
        }
        const int* mp = mask + (size_t)b * SEQ * SEQ + (size_t)(q0 + 4*ty) * SEQ + 4*tx;
#pragma unroll
        for (int i = 0; i < 4; ++i) mreg[i] = *(const int4*)(mp + i * SEQ);
    }

    for (int kv0 = 0; kv0 < SEQ; kv0 += TKV) {
        __syncthreads();   // previous PV done; LDS buffers free
#pragma unroll
        for (int jj = 0; jj < 4; ++jj) {
            Kts[ld0 + jj*4 + 0][lr] = kreg[jj].x;
            Kts[ld0 + jj*4 + 1][lr] = kreg[jj].y;
            Kts[ld0 + jj*4 + 2][lr] = kreg[jj].z;
            Kts[ld0 + jj*4 + 3][lr] = kreg[jj].w;
            *(float4*)&Vs[lr][ld0 + jj*4] = vreg[jj];
        }
        int4 mcur[4];
#pragma unroll
        for (int i = 0; i < 4; ++i) mcur[i] = mreg[i];
        __syncthreads();   // K/V visible

        if (kv0 + TKV < SEQ) {  // prefetch next tile; latency hides under S+PV
            const float* kp = Km + hbase + (size_t)(kv0 + TKV + lr) * D_MODEL + ld0;
            const float* vp = Vm + hbase + (size_t)(kv0 + TKV + lr) * D_MODEL + ld0;
#pragma unroll
            for (int jj = 0; jj < 4; ++jj) {
                kreg[jj] = *(const float4*)(kp + jj*4);
                vreg[jj] = *(const float4*)(vp + jj*4);
            }
            const int* mp = mask + (size_t)b * SEQ * SEQ + (size_t)(q0 + 4*ty) * SEQ
                          + (kv0 + TKV) + 4*tx;
#pragma unroll
            for (int i = 0; i < 4; ++i) mreg[i] = *(const int4*)(mp + i * SEQ);
        }

        // ---- S = Q K^T (rows 4ty+i, cols 4tx+j), outer-product over d ----
        float s[4][4];
#pragma unroll
        for (int i = 0; i < 4; ++i)
#pragma unroll
            for (int j = 0; j < 4; ++j) s[i][j] = 0.f;

#pragma unroll 16
        for (int d = 0; d < D_K; ++d) {
            float4 qa = *(const float4*)&Qst[d][4*ty];
            float4 kb = *(const float4*)&Kts[d][4*tx];
            const float aq[4]  = {qa.x, qa.y, qa.z, qa.w};
            const float bk4[4] = {kb.x, kb.y, kb.z, kb.w};
#pragma unroll
            for (int i = 0; i < 4; ++i)
#pragma unroll
                for (int j = 0; j < 4; ++j)
                    s[i][j] = fmaf(aq[i], bk4[j], s[i][j]);
        }

        // ---- scale + mask + online softmax (row reduce over tx lanes) ----
        float p[4][4];
#pragma unroll
        for (int i = 0; i < 4; ++i) {
            const int mi[4] = {mcur[i].x, mcur[i].y, mcur[i].z, mcur[i].w};
            float rmax = -1e30f;
#pragma unroll
            for (int j = 0; j < 4; ++j) {
                s[i][j] = (mi[j] == 0) ? -1e9f : s[i][j] * 0.03125f;  // 1/sqrt(1024)
                rmax = fmaxf(rmax, s[i][j]);
            }
            rmax = fmaxf(rmax, __shfl_xor(rmax, 1, 16));
            rmax = fmaxf(rmax, __shfl_xor(rmax, 2, 16));
            rmax = fmaxf(rmax, __shfl_xor(rmax, 4, 16));
            rmax = fmaxf(rmax, __shfl_xor(rmax, 8, 16));
            const float mnew = fmaxf(m_i[i], rmax);
            float rs = 0.f;
#pragma unroll
            for (int j = 0; j < 4; ++j) {
                p[i][j] = __expf(s[i][j] - mnew);
                rs += p[i][j];
            }
            rs += __shfl_xor(rs, 1, 16);
            rs += __shfl_xor(rs, 2, 16);
            rs += __shfl_xor(rs, 4, 16);
            rs += __shfl_xor(rs, 8, 16);
            const float alpha = __expf(m_i[i] - mnew);
            l_i[i] = l_i[i] * alpha + rs;
#pragma unroll
            for (int j = 0; j < 4; ++j) O[i][j] *= alpha;
            m_i[i] = mnew;
        }

        // ---- write P transposed: Pt[kcol][qrow] ----
#pragma unroll
        for (int j = 0; j < 4; ++j) {
            float4 col = make_float4(p[0][j], p[1][j], p[2][j], p[3][j]);
            *(float4*)&Pt[4*tx + j][4*ty] = col;
        }
        __syncthreads();   // Pt visible

        // ---- O += P V (rows 4ty+i, d-cols 4tx+j), outer-product over kc ----
#pragma unroll 16
        for (int kc = 0; kc < TKV; ++kc) {
            float4 pa = *(const float4*)&Pt[kc][4*ty];
            float4 vb = *(const float4*)&Vs[kc][4*tx];
            const float ap[4]  = {pa.x, pa.y, pa.z, pa.w};
            const float bv4[4] = {vb.x, vb.y, vb.z, vb.w};
#pragma unroll
            for (int i = 0; i < 4; ++i)
#pragma unroll
                for (int j = 0; j < 4; ++j)
                    O[i][j] = fmaf(ap[i], bv4[j], O[i][j]);
        }
    }

    // ---- normalize + write ctx in (B,S,H*dk) layout ----
#pragma unroll
    for (int i = 0; i < 4; ++i) {
        const float inv = 1.f / l_i[i];
        float4 o = make_float4(O[i][0]*inv, O[i][1]*inv, O[i][2]*inv, O[i][3]*inv);
        *(float4*)&ctx[hbase + (size_t)(q0 + 4*ty + i) * D_MODEL + 4*tx] = o;
    }
}

extern "C" void kernel_launch(void* const* d_in, const int* in_sizes, int n_in,
                              void* d_out, int out_size, void* d_ws, size_t ws_size,
                              hipStream_t stream)
{
    const float* q    = (const float*)d_in[0];
    const float* k    = (const float*)d_in[1];
    const float* v    = (const float*)d_in[2];
    const int*   mask = (const int*)  d_in[3];
    const float* Wq   = (const float*)d_in[4];
    const float* bq   = (const float*)d_in[5];
    const float* Wk   = (const float*)d_in[6];
    const float* bk   = (const float*)d_in[7];
    const float* Wv   = (const float*)d_in[8];
    const float* bv   = (const float*)d_in[9];
    const float* Wo   = (const float*)d_in[10];
    const float* bo   = (const float*)d_in[11];
    float* out = (float*)d_out;

    float* ws = (float*)d_ws;
    const size_t mat = (size_t)M_ROWS * D_MODEL;   // 4096*1024 floats = 16 MB
    float* Qp  = ws;                                // [M_ROWS][D_MODEL]
    float* Kp  = ws + mat;
    float* Vp  = ws + 2*mat;
    float* Ctx = ws + 3*mat;                        // total ws use: 64 MB

    dim3 gg(D_MODEL / BN, M_ROWS / BM);             // (8, 32)
    sgemm_nt_bias<<<gg, 256, 0, stream>>>(q, Wq, bq, Qp, M_ROWS, D_MODEL, D_MODEL);
    sgemm_nt_bias<<<gg, 256, 0, stream>>>(k, Wk, bk, Kp, M_ROWS, D_MODEL, D_MODEL);
    sgemm_nt_bias<<<gg, 256, 0, stream>>>(v, Wv, bv, Vp, M_ROWS, D_MODEL, D_MODEL);

    dim3 ga(SEQ / TKV, BATCH * N_HEAD);             // (32, 32)
    attn_fwd<<<ga, 256, 0, stream>>>(Qp, Kp, Vp, mask, Ctx);

    sgemm_nt_bias<<<gg, 256, 0, stream>>>(Ctx, Wo, bo, out, M_ROWS, D_MODEL, D_MODEL);
}

// Round 2
// 407.021 us; speedup vs baseline: 3.6553x; 3.6553x over previous
//
#include <hip/hip_runtime.h>

#define D_MODEL 1024
#define N_HEAD  16
#define D_K     64
#define BATCH   2
#define SEQ     2048
#define M_ROWS  (BATCH*SEQ)

typedef __attribute__((ext_vector_type(8))) short short8;   // 8 bf16 (4 VGPRs)
typedef __attribute__((ext_vector_type(4))) float f32x4;    // MFMA acc

// async global->LDS, 16B per lane; LDS dest is wave-uniform base + lane*16
#define GLDS16(gptr, lptr) \
    __builtin_amdgcn_global_load_lds((const __attribute__((address_space(1))) void*)(gptr), \
                                     (__attribute__((address_space(3))) void*)(lptr), 16, 0, 0)

__device__ __forceinline__ unsigned short f2bf(float f) {
    unsigned u = __builtin_bit_cast(unsigned, f);
    unsigned r = (u + 0x7fffu + ((u >> 16) & 1u)) >> 16;
    return (unsigned short)r;
}

// ---------------- fp32 -> bf16 conversion (4 elems/thread) ----------------
__global__ __launch_bounds__(256)
void cvt_bf16(const float* __restrict__ in, unsigned short* __restrict__ out, int n4)
{
    int i = blockIdx.x * blockDim.x + threadIdx.x;
    const int stride = gridDim.x * blockDim.x;
    for (; i < n4; i += stride) {
        float4 a = ((const float4*)in)[i];
        ushort4 o;
        o.x = f2bf(a.x); o.y = f2bf(a.y); o.z = f2bf(a.z); o.w = f2bf(a.w);
        ((ushort4*)out)[i] = o;
    }
}

// ---------------- mask (int32 0/1) -> bitmask (u64 per 64 cols) ----------------
__global__ __launch_bounds__(256)
void mask_pack(const int* __restrict__ mask, unsigned long long* __restrict__ mb, int nwords)
{
    const int lane = threadIdx.x & 63;
    int w = (blockIdx.x * blockDim.x + threadIdx.x) >> 6;
    const int nw = (gridDim.x * blockDim.x) >> 6;
    for (; w < nwords; w += nw) {
        int v = mask[(size_t)w * 64 + lane];
        unsigned long long bits = __ballot(v != 0);
        if (lane == 0) mb[w] = bits;
    }
}

// ---------------- bf16 MFMA GEMM: C[M][N] = A[M][K] @ W[N][K]^T + bias ----------------
// m97 structure: 128x128 tile, BK=32, 4 waves (2x2 of 64x64), global_load_lds w=16.
template<bool OUT_BF16, bool BIAS_ROW>
__global__ __launch_bounds__(256)
void gemm_bf16(const unsigned short* __restrict__ A, const unsigned short* __restrict__ W,
               const float* __restrict__ bias, void* __restrict__ Cout,
               int M, int N, int K)
{
    __shared__ unsigned short As[128 * 32];
    __shared__ unsigned short Ws[128 * 32];
    const int tid = threadIdx.x;
    const int l = tid & 63, w = tid >> 6;
    const int bm = blockIdx.y * 128, bn = blockIdx.x * 128;
    const int wr = (w >> 1) * 64, wc = (w & 1) * 64;

    // staging: thread t covers LDS bytes [t*16, t*16+16) (+issue*4096)
    const int srow = tid >> 2;            // 0..63
    const int scol = (tid & 3) * 8;       // elems
    const unsigned short* Ap = A + (size_t)(bm + srow) * K + scol;
    const unsigned short* Wp = W + (size_t)(bn + srow) * K + scol;
    char* AsB = (char*)As + w * 1024;     // wave-uniform LDS base
    char* WsB = (char*)Ws + w * 1024;

    f32x4 acc[4][4];
#pragma unroll
    for (int m = 0; m < 4; ++m)
#pragma unroll
        for (int n = 0; n < 4; ++n) acc[m][n] = (f32x4)0.0f;

    const int ro = l & 15, ge = (l >> 4) * 8;   // frag row-offset, k-group elems
    for (int k0 = 0; k0 < K; k0 += 32) {
        __syncthreads();                         // all waves done reading prev tile
        GLDS16(Ap + k0,                 AsB);
        GLDS16(Ap + k0 + (size_t)64 * K, AsB + 4096);
        GLDS16(Wp + k0,                 WsB);
        GLDS16(Wp + k0 + (size_t)64 * K, WsB + 4096);
        __syncthreads();                         // vmcnt drained before barrier -> LDS ready

        short8 a[4], b[4];
#pragma unroll
        for (int m = 0; m < 4; ++m)
            a[m] = *(const short8*)(As + (wr + m * 16 + ro) * 32 + ge);
#pragma unroll
        for (int n = 0; n < 4; ++n)
            b[n] = *(const short8*)(Ws + (wc + n * 16 + ro) * 32 + ge);
#pragma unroll
        for (int m = 0; m < 4; ++m)
#pragma unroll
            for (int n = 0; n < 4; ++n)
                acc[m][n] = __builtin_amdgcn_mfma_f32_16x16x32_bf16(a[m], b[n], acc[m][n], 0, 0, 0);
    }

    // epilogue: C row = (l>>4)*4 + j, col = l&15 within each 16x16 frag
    const int cr = (l >> 4) * 4;
#pragma unroll
    for (int m = 0; m < 4; ++m)
#pragma unroll
        for (int n = 0; n < 4; ++n)
#pragma unroll
            for (int j = 0; j < 4; ++j) {
                const int row = bm + wr + m * 16 + cr + j;
                const int col = bn + wc + n * 16 + ro;
                const float vvv = acc[m][n][j] + (BIAS_ROW ? bias[row] : bias[col]);
                if constexpr (OUT_BF16)
                    ((unsigned short*)Cout)[(size_t)row * N + col] = f2bf(vvv);
                else
                    ((float*)Cout)[(size_t)row * N + col] = vvv;
            }
}

// ---------------- bf16 MFMA flash attention ----------------
// block: 128 q-rows x one (b,h); 4 waves, wave owns 32 q-rows. KV tile = 64.
// All LDS tiles [rows][128B] with XOR swizzle byte^=(row&7)<<4, applied on BOTH
// the global_load_lds source column and every ds access (rule #21).
__global__ __launch_bounds__(256, 2)
void attn_mfma(const unsigned short* __restrict__ Qp, const unsigned short* __restrict__ Kp,
               const unsigned short* __restrict__ Vt, const unsigned long long* __restrict__ mb,
               unsigned short* __restrict__ Ctx)
{
    __shared__ char Qs[128 * 128];      // [128 q][64 d * 2B]
    __shared__ char Ks[64 * 128];       // [64 kcol][64 d]
    __shared__ char Vs[64 * 128];       // V^T: [64 d][64 kcol]
    __shared__ char Ps[4 * 32 * 128];   // per-wave [32 q][64 kcol]

    const int tid = threadIdx.x, l = tid & 63, w = tid >> 6;
    const int b = blockIdx.y >> 4, h = blockIdx.y & 15;
    const int q0 = blockIdx.x * 128;

    // staging geometry: thread t -> LDS row (t>>3)+32*issue, 16B slot t&7
    const int lrow = tid >> 3;                  // 0..31
    const int ss = (tid & 7) ^ (lrow & 7);      // pre-swizzled source slot
    const size_t tokbase = (size_t)b * SEQ;

    // ---- stage Q (16KB, 4 issues) + first K/V tile ----
    {
        const unsigned short* qsrc = Qp + (tokbase + q0 + lrow) * D_MODEL + h * 64 + ss * 8;
        char* qdst = Qs + w * 1024;
#pragma unroll
        for (int i = 0; i < 4; ++i)
            GLDS16(qsrc + (size_t)32 * i * D_MODEL, qdst + i * 4096);
    }
    {
        const unsigned short* ksrc = Kp + (tokbase + 0 + lrow) * D_MODEL + h * 64 + ss * 8;
        const unsigned short* vsrc = Vt + (size_t)(h * 64 + lrow) * M_ROWS + tokbase + 0 + ss * 8;
        GLDS16(ksrc,                          Ks + w * 1024);
        GLDS16(ksrc + (size_t)32 * D_MODEL,   Ks + w * 1024 + 4096);
        GLDS16(vsrc,                          Vs + w * 1024);
        GLDS16(vsrc + (size_t)32 * M_ROWS,    Vs + w * 1024 + 4096);
    }
    __syncthreads();

    const int ro = l & 15, gb = (l >> 4) * 16;  // frag row-offset, k-group byte offset

    // ---- hoist Q fragments (block-constant) ----
    short8 qf[2][2];
#pragma unroll
    for (int mi = 0; mi < 2; ++mi)
#pragma unroll
        for (int c = 0; c < 2; ++c) {
            const int row = w * 32 + mi * 16 + ro;
            const int cb = c * 64 + gb;
            qf[mi][c] = *(const short8*)(Qs + row * 128 + (cb ^ ((row & 7) << 4)));
        }

    f32x4 o[2][4];
    float m_s[2][4], l_s[2][4];
#pragma unroll
    for (int mi = 0; mi < 2; ++mi)
#pragma unroll
        for (int j = 0; j < 4; ++j) { m_s[mi][j] = -1e30f; l_s[mi][j] = 0.f; }
#pragma unroll
    for (int mi = 0; mi < 2; ++mi)
#pragma unroll
        for (int dn = 0; dn < 4; ++dn) o[mi][dn] = (f32x4)0.0f;

    for (int t = 0; t < SEQ / 64; ++t) {
        const int kv0 = t * 64;

        // ---- read K and V fragments for this tile ----
        short8 kf[4][2], vf[4][2];
#pragma unroll
        for (int n = 0; n < 4; ++n)
#pragma unroll
            for (int c = 0; c < 2; ++c) {
                const int row = n * 16 + ro;
                const int cb = c * 64 + gb;
                kf[n][c] = *(const short8*)(Ks + row * 128 + (cb ^ ((row & 7) << 4)));
                vf[n][c] = *(const short8*)(Vs + row * 128 + (cb ^ ((row & 7) << 4)));
            }

        // ---- mask words (u64 covers this tile's 64 cols for each of my 8 rows) ----
        unsigned long long mw[2][4];
#pragma unroll
        for (int mi = 0; mi < 2; ++mi)
#pragma unroll
            for (int j = 0; j < 4; ++j) {
                const int qr = q0 + w * 32 + mi * 16 + (l >> 4) * 4 + j;
                mw[mi][j] = mb[(tokbase + qr) * (SEQ / 64) + (kv0 >> 6)];
            }

        // ---- S = Q K^T ----
        f32x4 s[2][4];
#pragma unroll
        for (int mi = 0; mi < 2; ++mi)
#pragma unroll
            for (int n = 0; n < 4; ++n) {
                f32x4 acc = (f32x4)0.0f;
                acc = __builtin_amdgcn_mfma_f32_16x16x32_bf16(qf[mi][0], kf[n][0], acc, 0, 0, 0);
                acc = __builtin_amdgcn_mfma_f32_16x16x32_bf16(qf[mi][1], kf[n][1], acc, 0, 0, 0);
                s[mi][n] = acc;
            }

        __syncthreads();   // everyone done reading Ks/Vs -> safe to restage

        if (t + 1 < SEQ / 64) {   // prefetch next K/V; drains at loop-end barrier
            const int nv = kv0 + 64;
            const unsigned short* ksrc = Kp + (tokbase + nv + lrow) * D_MODEL + h * 64 + ss * 8;
            const unsigned short* vsrc = Vt + (size_t)(h * 64 + lrow) * M_ROWS + tokbase + nv + ss * 8;
            GLDS16(ksrc,                        Ks + w * 1024);
            GLDS16(ksrc + (size_t)32 * D_MODEL, Ks + w * 1024 + 4096);
            GLDS16(vsrc,                        Vs + w * 1024);
            GLDS16(vsrc + (size_t)32 * M_ROWS,  Vs + w * 1024 + 4096);
        }

        // ---- mask + scale + online softmax + P write (per-wave LDS, no barrier) ----
#pragma unroll
        for (int mi = 0; mi < 2; ++mi)
#pragma unroll
            for (int j = 0; j < 4; ++j) {
                const unsigned long long mwv = mw[mi][j];
                float sv0 = ((mwv >> (ro))      & 1) ? s[mi][0][j] * 0.03125f : -1e9f;
                float sv1 = ((mwv >> (16 + ro)) & 1) ? s[mi][1][j] * 0.03125f : -1e9f;
                float sv2 = ((mwv >> (32 + ro)) & 1) ? s[mi][2][j] * 0.03125f : -1e9f;
                float sv3 = ((mwv >> (48 + ro)) & 1) ? s[mi][3][j] * 0.03125f : -1e9f;
                float rmax = fmaxf(fmaxf(sv0, sv1), fmaxf(sv2, sv3));
                rmax = fmaxf(rmax, __shfl_xor(rmax, 1, 16));
                rmax = fmaxf(rmax, __shfl_xor(rmax, 2, 16));
                rmax = fmaxf(rmax, __shfl_xor(rmax, 4, 16));
                rmax = fmaxf(rmax, __shfl_xor(rmax, 8, 16));
                const float mold = m_s[mi][j];
                const float mnew = fmaxf(mold, rmax);
                const float al = __expf(mold - mnew);
                const float p0 = __expf(sv0 - mnew), p1 = __expf(sv1 - mnew);
                const float p2 = __expf(sv2 - mnew), p3 = __expf(sv3 - mnew);
                float rs = (p0 + p1) + (p2 + p3);
                rs += __shfl_xor(rs, 1, 16);
                rs += __shfl_xor(rs, 2, 16);
                rs += __shfl_xor(rs, 4, 16);
                rs += __shfl_xor(rs, 8, 16);
                l_s[mi][j] = l_s[mi][j] * al + rs;
                m_s[mi][j] = mnew;
                o[mi][0][j] *= al; o[mi][1][j] *= al;
                o[mi][2][j] *= al; o[mi][3][j] *= al;
                const int prow = mi * 16 + (l >> 4) * 4 + j;
                char* pb = Ps + w * 4096 + prow * 128;
                const int sw = (prow & 7) << 4;
                *(unsigned short*)(pb + (((0  + ro) * 2) ^ sw)) = f2bf(p0);
                *(unsigned short*)(pb + (((16 + ro) * 2) ^ sw)) = f2bf(p1);
                *(unsigned short*)(pb + (((32 + ro) * 2) ^ sw)) = f2bf(p2);
                *(unsigned short*)(pb + (((48 + ro) * 2) ^ sw)) = f2bf(p3);
            }

        // ---- O += P V  (P from per-wave LDS, V^T frags already in regs) ----
        short8 pf[2][2];
#pragma unroll
        for (int mi = 0; mi < 2; ++mi)
#pragma unroll
            for (int kc = 0; kc < 2; ++kc) {
                const int row = mi * 16 + ro;
                const int cb = kc * 64 + gb;
                pf[mi][kc] = *(const short8*)(Ps + w * 4096 + row * 128 + (cb ^ ((row & 7) << 4)));
            }
#pragma unroll
        for (int mi = 0; mi < 2; ++mi)
#pragma unroll
            for (int dn = 0; dn < 4; ++dn) {
                o[mi][dn] = __builtin_amdgcn_mfma_f32_16x16x32_bf16(pf[mi][0], vf[dn][0], o[mi][dn], 0, 0, 0);
                o[mi][dn] = __builtin_amdgcn_mfma_f32_16x16x32_bf16(pf[mi][1], vf[dn][1], o[mi][dn], 0, 0, 0);
            }

        __syncthreads();   // drains staging loads -> next tile's Ks/Vs ready
    }

    // ---- normalize + write ctx (bf16, token-major [B*S][D_MODEL]) ----
#pragma unroll
    for (int mi = 0; mi < 2; ++mi)
#pragma unroll
        for (int dn = 0; dn < 4; ++dn)
#pragma unroll
            for (int j = 0; j < 4; ++j) {
                const int qr = q0 + w * 32 + mi * 16 + (l >> 4) * 4 + j;
                const int col = h * 64 + dn * 16 + ro;
                const float val = o[mi][dn][j] / l_s[mi][j];
                Ctx[(tokbase + qr) * D_MODEL + col] = f2bf(val);
            }
}

extern "C" void kernel_launch(void* const* d_in, const int* in_sizes, int n_in,
                              void* d_out, int out_size, void* d_ws, size_t ws_size,
                              hipStream_t stream)
{
    const float* q    = (const float*)d_in[0];
    const float* k    = (const float*)d_in[1];
    const float* v    = (const float*)d_in[2];
    const int*   mask = (const int*)  d_in[3];
    const float* Wq   = (const float*)d_in[4];
    const float* bq   = (const float*)d_in[5];
    const float* Wk   = (const float*)d_in[6];
    const float* bk   = (const float*)d_in[7];
    const float* Wv   = (const float*)d_in[8];
    const float* bv   = (const float*)d_in[9];
    const float* Wo   = (const float*)d_in[10];
    const float* bo   = (const float*)d_in[11];
    float* out = (float*)d_out;

    unsigned short* ws16 = (unsigned short*)d_ws;
    const size_t M1 = 1024 * 1024;
    unsigned short* qb  = ws16;              // 4M elems
    unsigned short* kb  = ws16 + 4 * M1;
    unsigned short* vb  = ws16 + 8 * M1;
    unsigned short* Wqb = ws16 + 12 * M1;    // 1M each
    unsigned short* Wkb = ws16 + 13 * M1;
    unsigned short* Wvb = ws16 + 14 * M1;
    unsigned short* Wob = ws16 + 15 * M1;
    unsigned short* Qp  = ws16 + 16 * M1;    // 4M each
    unsigned short* Kp  = ws16 + 20 * M1;
    unsigned short* Vtp = ws16 + 24 * M1;    // V^T: [D_MODEL][M_ROWS]
    unsigned short* Ctx = qb;                           // alias: qb dead after Q-proj
    unsigned long long* maskb = (unsigned long long*)kb; // alias: kb dead after K-proj

    // fp32 -> bf16
    cvt_bf16<<<2048, 256, 0, stream>>>(q,  qb,  (int)(4 * M1 / 4));
    cvt_bf16<<<2048, 256, 0, stream>>>(k,  kb,  (int)(4 * M1 / 4));
    cvt_bf16<<<2048, 256, 0, stream>>>(v,  vb,  (int)(4 * M1 / 4));
    cvt_bf16<<<1024, 256, 0, stream>>>(Wq, Wqb, (int)(M1 / 4));
    cvt_bf16<<<1024, 256, 0, stream>>>(Wk, Wkb, (int)(M1 / 4));
    cvt_bf16<<<1024, 256, 0, stream>>>(Wv, Wvb, (int)(M1 / 4));
    cvt_bf16<<<1024, 256, 0, stream>>>(Wo, Wob, (int)(M1 / 4));

    // projections (bf16 out)
    dim3 g1(D_MODEL / 128, M_ROWS / 128);   // (8, 32)
    gemm_bf16<true, false><<<g1, 256, 0, stream>>>(qb, Wqb, bq, Qp, M_ROWS, D_MODEL, D_MODEL);
    gemm_bf16<true, false><<<g1, 256, 0, stream>>>(kb, Wkb, bk, Kp, M_ROWS, D_MODEL, D_MODEL);
    // V^T = Wv @ v^T  (swapped operands; bias indexed by row)
    dim3 g2(M_ROWS / 128, D_MODEL / 128);   // (32, 8)
    gemm_bf16<true, true><<<g2, 256, 0, stream>>>(Wvb, vb, bv, Vtp, D_MODEL, M_ROWS, D_MODEL);

    // mask -> bitmask (after K-proj: maskb aliases kb)
    mask_pack<<<512, 256, 0, stream>>>(mask, maskb, BATCH * SEQ * SEQ / 64);

    // attention
    dim3 ga(SEQ / 128, BATCH * N_HEAD);     // (16, 32)
    attn_mfma<<<ga, 256, 0, stream>>>(Qp, Kp, Vtp, maskb, Ctx);

    // output projection (fp32 out)
    gemm_bf16<false, false><<<g1, 256, 0, stream>>>(Ctx, Wob, bo, out, M_ROWS, D_MODEL, D_MODEL);
}

// Round 3
// 325.113 us; speedup vs baseline: 4.5762x; 1.2519x over previous
//
#include <hip/hip_runtime.h>

#define D_MODEL 1024
#define N_HEAD  16
#define D_K     64
#define BATCH   2
#define SEQ     2048
#define M_ROWS  (BATCH*SEQ)
#define NT      (SEQ/64)

typedef __attribute__((ext_vector_type(8))) short short8;   // 8 bf16
typedef __attribute__((ext_vector_type(4))) float f32x4;
typedef unsigned short u16;
typedef unsigned long long u64;

#define GLDS16(g, l) \
    __builtin_amdgcn_global_load_lds((const __attribute__((address_space(1))) void*)(g), \
                                     (__attribute__((address_space(3))) void*)(l), 16, 0, 0)

__device__ __forceinline__ u16 f2bf(float f) {
    unsigned u = __builtin_bit_cast(unsigned, f);
    unsigned r = (u + 0x7fffu + ((u >> 16) & 1u)) >> 16;
    return (u16)r;
}

__device__ __forceinline__ float fexp2(float x) {
#if __has_builtin(__builtin_amdgcn_exp2f)
    return __builtin_amdgcn_exp2f(x);
#else
    return exp2f(x);
#endif
}

// ---- DPP 16-lane row reductions (1-cy VALU ops; avoids ds_swizzle shfl chains) ----
template<int CTRL>
__device__ __forceinline__ float dppmov(float x) {
    return __builtin_bit_cast(float,
        __builtin_amdgcn_mov_dpp(__builtin_bit_cast(int, x), CTRL, 0xf, 0xf, true));
}
__device__ __forceinline__ float rowmax16(float x) {
    x = fmaxf(x, dppmov<0xB1>(x));    // quad_perm(1,0,3,2)  xor1
    x = fmaxf(x, dppmov<0x4E>(x));    // quad_perm(2,3,0,1)  xor2
    x = fmaxf(x, dppmov<0x124>(x));   // row_ror:4
    x = fmaxf(x, dppmov<0x128>(x));   // row_ror:8
    return x;
}
__device__ __forceinline__ float rowsum16(float x) {
    x += dppmov<0xB1>(x);
    x += dppmov<0x4E>(x);
    x += dppmov<0x124>(x);
    x += dppmov<0x128>(x);
    return x;
}

// ---------------- fused fp32->bf16 conversion for all 7 tensors ----------------
__global__ __launch_bounds__(256)
void cvt_all(const float* __restrict__ q, const float* __restrict__ k, const float* __restrict__ v,
             const float* __restrict__ wq, const float* __restrict__ wk,
             const float* __restrict__ wv, const float* __restrict__ wo,
             u16* __restrict__ qb, u16* __restrict__ kb, u16* __restrict__ vb,
             u16* __restrict__ wqb, u16* __restrict__ wkb, u16* __restrict__ wvb, u16* __restrict__ wob)
{
    const int total = 3 * 1048576 + 4 * 262144;   // in float4 units
    int i = blockIdx.x * blockDim.x + threadIdx.x;
    const int stride = gridDim.x * blockDim.x;
    for (; i < total; i += stride) {
        const float* src; u16* dst; int loc;
        if (i < 3 * 1048576) {
            const int t = i >> 20; loc = i & 1048575;
            src = (t == 0) ? q : (t == 1) ? k : v;
            dst = (t == 0) ? qb : (t == 1) ? kb : vb;
        } else {
            const int j = i - 3 * 1048576; const int t = j >> 18; loc = j & 262143;
            src = (t == 0) ? wq : (t == 1) ? wk : (t == 2) ? wv : wo;
            dst = (t == 0) ? wqb : (t == 1) ? wkb : (t == 2) ? wvb : wob;
        }
        float4 a = ((const float4*)src)[loc];
        ushort4 o;
        o.x = f2bf(a.x); o.y = f2bf(a.y); o.z = f2bf(a.z); o.w = f2bf(a.w);
        ((ushort4*)dst)[loc] = o;
    }
}

// ---------------- mask (int32 0/1) -> bitmask ----------------
__global__ __launch_bounds__(256)
void mask_pack(const int* __restrict__ mask, u64* __restrict__ mb, int nwords)
{
    const int lane = threadIdx.x & 63;
    int w = (blockIdx.x * blockDim.x + threadIdx.x) >> 6;
    const int nw = (gridDim.x * blockDim.x) >> 6;
    for (; w < nwords; w += nw) {
        int v = mask[(size_t)w * 64 + lane];
        u64 bits = __ballot(v != 0);
        if (lane == 0) mb[w] = bits;
    }
}

// ---------------- bf16 MFMA GEMM body: C[M][N] = A[M][K] @ W[N][K]^T + bias ----------------
// 128x64 tile, BK=32, 4 waves (2x2 of 64x32), double-buffered LDS, 1 barrier/K-step.
template<bool OUT_BF16, bool BIAS_ROW>
__device__ __forceinline__
void gemm_body(const u16* __restrict__ A, const u16* __restrict__ W,
               const float* __restrict__ bias, void* __restrict__ Cout,
               const int M, const int N, const int K, const int bx, const int by)
{
    __shared__ u16 As[2][128 * 32];
    __shared__ u16 Ws[2][64 * 32];
    const int tid = threadIdx.x, l = tid & 63, w = tid >> 6;
    const int bm = by * 128, bn = bx * 64;
    const int wr = (w >> 1) * 64, wc = (w & 1) * 32;

    const int srow = tid >> 2, scol = (tid & 3) * 8;
    const u16* Ap = A + (size_t)(bm + srow) * K + scol;
    const u16* Wp = W + (size_t)(bn + srow) * K + scol;

    f32x4 acc[4][2];
#pragma unroll
    for (int m = 0; m < 4; ++m)
#pragma unroll
        for (int n = 0; n < 2; ++n) acc[m][n] = (f32x4)0.0f;

    const int ro = l & 15, ge = (l >> 4) * 8;

    // prologue: stage K-step 0 into buf 0
    GLDS16(Ap,                  (char*)As[0] + w * 1024);
    GLDS16(Ap + (size_t)64 * K, (char*)As[0] + w * 1024 + 4096);
    GLDS16(Wp,                  (char*)Ws[0] + w * 1024);
    __syncthreads();

    int buf = 0;
    for (int k0 = 0; k0 < K; k0 += 32) {
        if (k0 + 32 < K) {   // prefetch next step into other buffer
            GLDS16(Ap + k0 + 32,                  (char*)As[buf ^ 1] + w * 1024);
            GLDS16(Ap + k0 + 32 + (size_t)64 * K, (char*)As[buf ^ 1] + w * 1024 + 4096);
            GLDS16(Wp + k0 + 32,                  (char*)Ws[buf ^ 1] + w * 1024);
        }
        short8 a[4], b[2];
#pragma unroll
        for (int m = 0; m < 4; ++m)
            a[m] = *(const short8*)(As[buf] + (wr + m * 16 + ro) * 32 + ge);
#pragma unroll
        for (int n = 0; n < 2; ++n)
            b[n] = *(const short8*)(Ws[buf] + (wc + n * 16 + ro) * 32 + ge);
#pragma unroll
        for (int m = 0; m < 4; ++m)
#pragma unroll
            for (int n = 0; n < 2; ++n)
                acc[m][n] = __builtin_amdgcn_mfma_f32_16x16x32_bf16(a[m], b[n], acc[m][n], 0, 0, 0);
        __syncthreads();   // drains prefetch (vmcnt) + protects buf reuse
        buf ^= 1;
    }

    const int cr = (l >> 4) * 4;
#pragma unroll
    for (int m = 0; m < 4; ++m)
#pragma unroll
        for (int n = 0; n < 2; ++n)
#pragma unroll
            for (int j = 0; j < 4; ++j) {
                const int row = bm + wr + m * 16 + cr + j;
                const int col = bn + wc + n * 16 + ro;
                const float vvv = acc[m][n][j] + (BIAS_ROW ? bias[row] : bias[col]);
                if constexpr (OUT_BF16)
                    ((u16*)Cout)[(size_t)row * N + col] = f2bf(vvv);
                else
                    ((float*)Cout)[(size_t)row * N + col] = vvv;
            }
}

__device__ __forceinline__ void xcd_swizzle(int gx, int gy, int& bx, int& by)
{
    int lin = blockIdx.y * gx + blockIdx.x;
    const int nwg = gx * gy;            // multiple of 8 in all our launches
    const int cpx = nwg >> 3;
    lin = (lin & 7) * cpx + (lin >> 3); // chunked: consecutive work per XCD
    bx = lin % gx; by = lin / gx;
}

// fused Q,K projections: grid (16, 32, 2)
__global__ __launch_bounds__(256)
void gemm_qk(const u16* __restrict__ qb, const u16* __restrict__ kb,
             const u16* __restrict__ wqb, const u16* __restrict__ wkb,
             const float* __restrict__ bq, const float* __restrict__ bk,
             u16* __restrict__ Qp, u16* __restrict__ Kp)
{
    int bx, by; xcd_swizzle(gridDim.x, gridDim.y, bx, by);
    const int z = blockIdx.z;
    gemm_body<true, false>(z ? kb : qb, z ? wkb : wqb, z ? bk : bq,
                           z ? Kp : Qp, M_ROWS, D_MODEL, D_MODEL, bx, by);
}

// V^T = Wv @ v^T : grid (64, 8)
__global__ __launch_bounds__(256)
void gemm_vt(const u16* __restrict__ wvb, const u16* __restrict__ vb,
             const float* __restrict__ bv, u16* __restrict__ Vt)
{
    int bx, by; xcd_swizzle(gridDim.x, gridDim.y, bx, by);
    gemm_body<true, true>(wvb, vb, bv, Vt, D_MODEL, M_ROWS, D_MODEL, bx, by);
}

// output projection: grid (16, 32), fp32 out
__global__ __launch_bounds__(256)
void gemm_out(const u16* __restrict__ Ctx, const u16* __restrict__ wob,
              const float* __restrict__ bo, float* __restrict__ out)
{
    int bx, by; xcd_swizzle(gridDim.x, gridDim.y, bx, by);
    gemm_body<false, false>(Ctx, wob, bo, out, M_ROWS, D_MODEL, D_MODEL, bx, by);
}

// ---------------- bf16 MFMA flash attention ----------------
// Q-block 64 rows, 4 waves (16 rows each), KV tile 64, double-buffered K/V (1 barrier/tile),
// Q-tile LDS reused as per-wave P buffer after the fragment hoist. 40KB LDS -> 4 blocks/CU.
__global__ __launch_bounds__(256, 4)
void attn_mfma(const u16* __restrict__ Qp, const u16* __restrict__ Kp,
               const u16* __restrict__ Vt, const u64* __restrict__ mb,
               u16* __restrict__ Ctx)
{
    __shared__ char QsPs[8192];     // Q tile 64x128B; after hoist: per-wave P [16][128B]
    __shared__ char Ks[2][8192];    // [64 kcol][64 d]
    __shared__ char Vs[2][8192];    // V^T [64 d][64 kcol]

    const int tid = threadIdx.x, l = tid & 63, w = tid >> 6;
    int lin = blockIdx.y * gridDim.x + blockIdx.x;
    lin = (lin & 7) * 128 + (lin >> 3);          // 1024 wgs, 128/XCD (same (b,h) contiguous)
    const int bx = lin & 31, by = lin >> 5;
    const int b = by >> 4, h = by & 15;
    const int q0 = bx * 64;
    const size_t tokbase = (size_t)b * SEQ;

    const int lrow = tid >> 3, ss = (tid & 7) ^ (lrow & 7);   // pre-swizzled source slot
    const u16* ksrc0 = Kp + (tokbase + lrow) * D_MODEL + h * 64 + ss * 8;
    const u16* vsrc0 = Vt + (size_t)(h * 64 + lrow) * M_ROWS + tokbase + ss * 8;

    { // prologue: stage Q + first K/V tile
        const u16* qsrc = Qp + (tokbase + q0 + lrow) * D_MODEL + h * 64 + ss * 8;
        GLDS16(qsrc,                          QsPs + w * 1024);
        GLDS16(qsrc + (size_t)32 * D_MODEL,   QsPs + w * 1024 + 4096);
        GLDS16(ksrc0,                         (char*)Ks[0] + w * 1024);
        GLDS16(ksrc0 + (size_t)32 * D_MODEL,  (char*)Ks[0] + w * 1024 + 4096);
        GLDS16(vsrc0,                         (char*)Vs[0] + w * 1024);
        GLDS16(vsrc0 + (size_t)32 * M_ROWS,   (char*)Vs[0] + w * 1024 + 4096);
    }
    __syncthreads();

    const int ro = l & 15, gb = (l >> 4) * 16;

    // hoist Q fragments (wave reads only its own 16 rows = its own future P region)
    short8 qf[2];
#pragma unroll
    for (int c = 0; c < 2; ++c) {
        const int row = w * 16 + ro;
        qf[c] = *(const short8*)(QsPs + row * 128 + ((c * 64 + gb) ^ ((row & 7) << 4)));
    }

    size_t mbase[4];
#pragma unroll
    for (int j = 0; j < 4; ++j)
        mbase[j] = (tokbase + q0 + w * 16 + (l >> 4) * 4 + j) * (size_t)NT;

    f32x4 o[4];
    float m_s[4], l_s[4];
#pragma unroll
    for (int j = 0; j < 4; ++j) { m_s[j] = -1e30f; l_s[j] = 0.f; }
#pragma unroll
    for (int dn = 0; dn < 4; ++dn) o[dn] = (f32x4)0.0f;

    constexpr float CSC = 0.03125f * 1.44269504089f;   // 1/sqrt(1024) * log2(e)

    for (int t = 0; t < NT; ++t) {
        const int cur = t & 1;
        if (t + 1 < NT) {   // prefetch next K/V tile into the other buffer
            const u16* kn = ksrc0 + (size_t)(t + 1) * 64 * D_MODEL;
            const u16* vn = vsrc0 + (t + 1) * 64;
            GLDS16(kn,                         (char*)Ks[cur ^ 1] + w * 1024);
            GLDS16(kn + (size_t)32 * D_MODEL,  (char*)Ks[cur ^ 1] + w * 1024 + 4096);
            GLDS16(vn,                         (char*)Vs[cur ^ 1] + w * 1024);
            GLDS16(vn + (size_t)32 * M_ROWS,   (char*)Vs[cur ^ 1] + w * 1024 + 4096);
        }

        u64 mw[4];
#pragma unroll
        for (int j = 0; j < 4; ++j) mw[j] = mb[mbase[j] + t];

        // ---- S = Q K^T ----
        f32x4 s[4];
#pragma unroll
        for (int n = 0; n < 4; ++n) {
            const int row = n * 16 + ro;
            short8 k0f = *(const short8*)(Ks[cur] + row * 128 + ((gb)      ^ ((row & 7) << 4)));
            short8 k1f = *(const short8*)(Ks[cur] + row * 128 + ((64 + gb) ^ ((row & 7) << 4)));
            f32x4 a = (f32x4)0.0f;
            a = __builtin_amdgcn_mfma_f32_16x16x32_bf16(qf[0], k0f, a, 0, 0, 0);
            a = __builtin_amdgcn_mfma_f32_16x16x32_bf16(qf[1], k1f, a, 0, 0, 0);
            s[n] = a;
        }

        // ---- mask + scale (exp2 domain) + row max (DPP) ----
        float rmx[4];
        int pred = 1;
#pragma unroll
        for (int j = 0; j < 4; ++j) {
            const u64 t64 = mw[j] >> ro;
#pragma unroll
            for (int n = 0; n < 4; ++n)
                s[n][j] = ((t64 >> (n * 16)) & 1) ? s[n][j] * CSC : -1e9f;
            float rm = fmaxf(fmaxf(s[0][j], s[1][j]), fmaxf(s[2][j], s[3][j]));
            rm = rowmax16(rm);
            rmx[j] = rm;
            pred &= (rm <= m_s[j] + 8.f);
        }
        if (!__all(pred)) {   // rescale only when max grew past threshold (T13)
#pragma unroll
            for (int j = 0; j < 4; ++j) {
                const float mn = fmaxf(m_s[j], rmx[j]);
                const float al = fexp2(m_s[j] - mn);
                m_s[j] = mn; l_s[j] *= al;
                o[0][j] *= al; o[1][j] *= al; o[2][j] *= al; o[3][j] *= al;
            }
        }

        // ---- P = exp2(S - m), row sums (DPP), write P to per-wave LDS ----
        char* pb = QsPs + w * 2048;
#pragma unroll
        for (int j = 0; j < 4; ++j) {
            const int prow = (l >> 4) * 4 + j;
            const int sw = (prow & 7) << 4;
            const float p0 = fexp2(s[0][j] - m_s[j]);
            const float p1 = fexp2(s[1][j] - m_s[j]);
            const float p2 = fexp2(s[2][j] - m_s[j]);
            const float p3 = fexp2(s[3][j] - m_s[j]);
            float rs = (p0 + p1) + (p2 + p3);
            rs = rowsum16(rs);
            l_s[j] += rs;
            *(u16*)(pb + prow * 128 + ((2 * (0  + ro)) ^ sw)) = f2bf(p0);
            *(u16*)(pb + prow * 128 + ((2 * (16 + ro)) ^ sw)) = f2bf(p1);
            *(u16*)(pb + prow * 128 + ((2 * (32 + ro)) ^ sw)) = f2bf(p2);
            *(u16*)(pb + prow * 128 + ((2 * (48 + ro)) ^ sw)) = f2bf(p3);
        }

        // ---- O += P V ----
        short8 pf[2];
#pragma unroll
        for (int c = 0; c < 2; ++c)
            pf[c] = *(const short8*)(pb + ro * 128 + ((c * 64 + gb) ^ ((ro & 7) << 4)));
#pragma unroll
        for (int dn = 0; dn < 4; ++dn) {
            const int row = dn * 16 + ro;
            short8 v0f = *(const short8*)(Vs[cur] + row * 128 + ((gb)      ^ ((row & 7) << 4)));
            short8 v1f = *(const short8*)(Vs[cur] + row * 128 + ((64 + gb) ^ ((row & 7) << 4)));
            o[dn] = __builtin_amdgcn_mfma_f32_16x16x32_bf16(pf[0], v0f, o[dn], 0, 0, 0);
            o[dn] = __builtin_amdgcn_mfma_f32_16x16x32_bf16(pf[1], v1f, o[dn], 0, 0, 0);
        }

        __syncthreads();   // drains prefetch; protects buffer reuse
    }

    // ---- normalize + write ctx (bf16, [B*S][D_MODEL]) ----
    float inv[4];
#pragma unroll
    for (int j = 0; j < 4; ++j) inv[j] = 1.f / l_s[j];
#pragma unroll
    for (int dn = 0; dn < 4; ++dn)
#pragma unroll
        for (int j = 0; j < 4; ++j) {
            const size_t qr = tokbase + q0 + w * 16 + (l >> 4) * 4 + j;
            Ctx[qr * D_MODEL + h * 64 + dn * 16 + ro] = f2bf(o[dn][j] * inv[j]);
        }
}

extern "C" void kernel_launch(void* const* d_in, const int* in_sizes, int n_in,
                              void* d_out, int out_size, void* d_ws, size_t ws_size,
                              hipStream_t stream)
{
    const float* q    = (const float*)d_in[0];
    const float* k    = (const float*)d_in[1];
    const float* v    = (const float*)d_in[2];
    const int*   mask = (const int*)  d_in[3];
    const float* Wq   = (const float*)d_in[4];
    const float* bq   = (const float*)d_in[5];
    const float* Wk   = (const float*)d_in[6];
    const float* bk   = (const float*)d_in[7];
    const float* Wv   = (const float*)d_in[8];
    const float* bv   = (const float*)d_in[9];
    const float* Wo   = (const float*)d_in[10];
    const float* bo   = (const float*)d_in[11];
    float* out = (float*)d_out;

    u16* ws16 = (u16*)d_ws;
    const size_t M1 = 1024 * 1024;
    u16* qb  = ws16;               // 4M elems each
    u16* kb  = ws16 + 4 * M1;
    u16* vb  = ws16 + 8 * M1;
    u16* Wqb = ws16 + 12 * M1;     // 1M each
    u16* Wkb = ws16 + 13 * M1;
    u16* Wvb = ws16 + 14 * M1;
    u16* Wob = ws16 + 15 * M1;
    u16* Qp  = ws16 + 16 * M1;
    u16* Kp  = ws16 + 20 * M1;
    u16* Vt  = ws16 + 24 * M1;     // V^T [D_MODEL][M_ROWS]
    u16* Ctx = qb;                               // qb dead after gemm_qk
    u64* maskb = (u64*)vb;                       // vb dead after gemm_vt

    cvt_all<<<2048, 256, 0, stream>>>(q, k, v, Wq, Wk, Wv, Wo,
                                      qb, kb, vb, Wqb, Wkb, Wvb, Wob);

    dim3 gqk(D_MODEL / 64, M_ROWS / 128, 2);    // (16, 32, 2) = 1024 blocks
    gemm_qk<<<gqk, 256, 0, stream>>>(qb, kb, Wqb, Wkb, bq, bk, Qp, Kp);

    dim3 gvt(M_ROWS / 64, D_MODEL / 128);       // (64, 8) = 512 blocks
    gemm_vt<<<gvt, 256, 0, stream>>>(Wvb, vb, bv, Vt);

    mask_pack<<<1024, 256, 0, stream>>>(mask, maskb, BATCH * SEQ * SEQ / 64);

    dim3 ga(SEQ / 64, BATCH * N_HEAD);          // (32, 32) = 1024 blocks
    attn_mfma<<<ga, 256, 0, stream>>>(Qp, Kp, Vt, maskb, Ctx);

    dim3 go(D_MODEL / 64, M_ROWS / 128);        // (16, 32) = 512 blocks
    gemm_out<<<go, 256, 0, stream>>>(Ctx, Wob, bo, out);
}

// Round 4
// 306.069 us; speedup vs baseline: 4.8609x; 1.0622x over previous
//
#include <hip/hip_runtime.h>

#define D_MODEL 1024
#define N_HEAD  16
#define D_K     64
#define BATCH   2
#define SEQ     2048
#define M_ROWS  (BATCH*SEQ)
#define NT      (SEQ/64)

typedef __attribute__((ext_vector_type(8))) short short8;   // 8 bf16
typedef __attribute__((ext_vector_type(4))) float f32x4;
typedef unsigned short u16;
typedef unsigned long long u64;

#define GLDS16(g, l) \
    __builtin_amdgcn_global_load_lds((const __attribute__((address_space(1))) void*)(g), \
                                     (__attribute__((address_space(3))) void*)(l), 16, 0, 0)

// 1/sqrt(1024) * log2(e): folded into the Q projection output
#define CSC (0.03125f * 1.44269504089f)

__device__ __forceinline__ u16 f2bf(float f) {
    unsigned u = __builtin_bit_cast(unsigned, f);
    unsigned r = (u + 0x7fffu + ((u >> 16) & 1u)) >> 16;
    return (u16)r;
}

__device__ __forceinline__ float fexp2(float x) {
#if __has_builtin(__builtin_amdgcn_exp2f)
    return __builtin_amdgcn_exp2f(x);
#else
    return exp2f(x);
#endif
}

// ---------------- fused fp32->bf16 conversion for all 7 tensors ----------------
__global__ __launch_bounds__(256)
void cvt_all(const float* __restrict__ q, const float* __restrict__ k, const float* __restrict__ v,
             const float* __restrict__ wq, const float* __restrict__ wk,
             const float* __restrict__ wv, const float* __restrict__ wo,
             u16* __restrict__ qb, u16* __restrict__ kb, u16* __restrict__ vb,
             u16* __restrict__ wqb, u16* __restrict__ wkb, u16* __restrict__ wvb, u16* __restrict__ wob)
{
    const int total = 3 * 1048576 + 4 * 262144;   // float4 units
    int i = blockIdx.x * blockDim.x + threadIdx.x;
    const int stride = gridDim.x * blockDim.x;
    for (; i < total; i += stride) {
        const float* src; u16* dst; int loc;
        if (i < 3 * 1048576) {
            const int t = i >> 20; loc = i & 1048575;
            src = (t == 0) ? q : (t == 1) ? k : v;
            dst = (t == 0) ? qb : (t == 1) ? kb : vb;
        } else {
            const int j = i - 3 * 1048576; const int t = j >> 18; loc = j & 262143;
            src = (t == 0) ? wq : (t == 1) ? wk : (t == 2) ? wv : wo;
            dst = (t == 0) ? wqb : (t == 1) ? wkb : (t == 2) ? wvb : wob;
        }
        float4 a = ((const float4*)src)[loc];
        ushort4 o;
        o.x = f2bf(a.x); o.y = f2bf(a.y); o.z = f2bf(a.z); o.w = f2bf(a.w);
        ((ushort4*)dst)[loc] = o;
    }
}

// ---------------- mask (int32 0/1) -> bitmask ----------------
__global__ __launch_bounds__(256)
void mask_pack(const int* __restrict__ mask, u64* __restrict__ mb, int nwords)
{
    const int lane = threadIdx.x & 63;
    int w = (blockIdx.x * blockDim.x + threadIdx.x) >> 6;
    const int nw = (gridDim.x * blockDim.x) >> 6;
    for (; w < nwords; w += nw) {
        int v = mask[(size_t)w * 64 + lane];
        u64 bits = __ballot(v != 0);
        if (lane == 0) mb[w] = bits;
    }
}

// ---------------- 128x128 bf16 MFMA GEMM body (m97 structure, dbuf, 1 barrier/step) ----
template<bool OUT_BF16, bool BIAS_ROW, bool SCALE>
__device__ __forceinline__
void gemm128_body(const u16* __restrict__ A, const u16* __restrict__ W,
                  const float* __restrict__ bias, void* __restrict__ Cout,
                  const int M, const int N, const int K, const int bx, const int by)
{
    __shared__ u16 As[2][128 * 32];
    __shared__ u16 Ws[2][128 * 32];
    const int tid = threadIdx.x, l = tid & 63, w = tid >> 6;
    const int bm = by * 128, bn = bx * 128;
    const int wr = (w >> 1) * 64, wc = (w & 1) * 64;
    const int srow = tid >> 2, scol = (tid & 3) * 8;
    const u16* Ap = A + (size_t)(bm + srow) * K + scol;
    const u16* Wp = W + (size_t)(bn + srow) * K + scol;

    f32x4 acc[4][4];
#pragma unroll
    for (int m = 0; m < 4; ++m)
#pragma unroll
        for (int n = 0; n < 4; ++n) acc[m][n] = (f32x4)0.0f;

    const int ro = l & 15, ge = (l >> 4) * 8;

    GLDS16(Ap,                  (char*)As[0] + w * 1024);
    GLDS16(Ap + (size_t)64 * K, (char*)As[0] + w * 1024 + 4096);
    GLDS16(Wp,                  (char*)Ws[0] + w * 1024);
    GLDS16(Wp + (size_t)64 * K, (char*)Ws[0] + w * 1024 + 4096);
    __syncthreads();

    int buf = 0;
    for (int k0 = 0; k0 < K; k0 += 32) {
        if (k0 + 32 < K) {
            GLDS16(Ap + k0 + 32,                  (char*)As[buf ^ 1] + w * 1024);
            GLDS16(Ap + k0 + 32 + (size_t)64 * K, (char*)As[buf ^ 1] + w * 1024 + 4096);
            GLDS16(Wp + k0 + 32,                  (char*)Ws[buf ^ 1] + w * 1024);
            GLDS16(Wp + k0 + 32 + (size_t)64 * K, (char*)Ws[buf ^ 1] + w * 1024 + 4096);
        }
        short8 a[4], b[4];
#pragma unroll
        for (int m = 0; m < 4; ++m)
            a[m] = *(const short8*)(As[buf] + (wr + m * 16 + ro) * 32 + ge);
#pragma unroll
        for (int n = 0; n < 4; ++n)
            b[n] = *(const short8*)(Ws[buf] + (wc + n * 16 + ro) * 32 + ge);
#pragma unroll
        for (int m = 0; m < 4; ++m)
#pragma unroll
            for (int n = 0; n < 4; ++n)
                acc[m][n] = __builtin_amdgcn_mfma_f32_16x16x32_bf16(a[m], b[n], acc[m][n], 0, 0, 0);
        __syncthreads();
        buf ^= 1;
    }

    const int cr = (l >> 4) * 4;
#pragma unroll
    for (int m = 0; m < 4; ++m)
#pragma unroll
        for (int n = 0; n < 4; ++n)
#pragma unroll
            for (int j = 0; j < 4; ++j) {
                const int row = bm + wr + m * 16 + cr + j;
                const int col = bn + wc + n * 16 + ro;
                float vvv = acc[m][n][j] + (BIAS_ROW ? bias[row] : bias[col]);
                if constexpr (SCALE) vvv *= CSC;
                if constexpr (OUT_BF16)
                    ((u16*)Cout)[(size_t)row * N + col] = f2bf(vvv);
                else
                    ((float*)Cout)[(size_t)row * N + col] = vvv;
            }
}

// fused Q,K,V^T projections: grid (256, 3)
__global__ __launch_bounds__(256)
void gemm_proj(const u16* __restrict__ qb, const u16* __restrict__ kb, const u16* __restrict__ vb,
               const u16* __restrict__ wqb, const u16* __restrict__ wkb, const u16* __restrict__ wvb,
               const float* __restrict__ bq, const float* __restrict__ bk, const float* __restrict__ bv,
               u16* __restrict__ Qp, u16* __restrict__ Kp, u16* __restrict__ Vt)
{
    int lin = blockIdx.x;
    lin = (lin & 7) * 32 + (lin >> 3);   // XCD-chunked
    const int z = blockIdx.y;
    if (z == 0)       // Q projection, pre-scaled by CSC
        gemm128_body<true, false, true >(qb, wqb, bq, Qp, M_ROWS, D_MODEL, D_MODEL, lin & 7, lin >> 3);
    else if (z == 1)  // K projection
        gemm128_body<true, false, false>(kb, wkb, bk, Kp, M_ROWS, D_MODEL, D_MODEL, lin & 7, lin >> 3);
    else              // V^T = Wv @ v^T  (bias per row)
        gemm128_body<true, true,  false>(wvb, vb, bv, Vt, D_MODEL, M_ROWS, D_MODEL, lin & 31, lin >> 5);
}

// ---------------- 128x64 GEMM for the output projection (512 blocks) ----------------
__device__ __forceinline__
void gemm64_body(const u16* __restrict__ A, const u16* __restrict__ W,
                 const float* __restrict__ bias, float* __restrict__ Cout,
                 const int N, const int K, const int bx, const int by)
{
    __shared__ u16 As[2][128 * 32];
    __shared__ u16 Ws[2][64 * 32];
    const int tid = threadIdx.x, l = tid & 63, w = tid >> 6;
    const int bm = by * 128, bn = bx * 64;
    const int wr = (w >> 1) * 64, wc = (w & 1) * 32;
    const int srow = tid >> 2, scol = (tid & 3) * 8;
    const u16* Ap = A + (size_t)(bm + srow) * K + scol;
    const u16* Wp = W + (size_t)(bn + srow) * K + scol;

    f32x4 acc[4][2];
#pragma unroll
    for (int m = 0; m < 4; ++m)
#pragma unroll
        for (int n = 0; n < 2; ++n) acc[m][n] = (f32x4)0.0f;

    const int ro = l & 15, ge = (l >> 4) * 8;

    GLDS16(Ap,                  (char*)As[0] + w * 1024);
    GLDS16(Ap + (size_t)64 * K, (char*)As[0] + w * 1024 + 4096);
    GLDS16(Wp,                  (char*)Ws[0] + w * 1024);
    __syncthreads();

    int buf = 0;
    for (int k0 = 0; k0 < K; k0 += 32) {
        if (k0 + 32 < K) {
            GLDS16(Ap + k0 + 32,                  (char*)As[buf ^ 1] + w * 1024);
            GLDS16(Ap + k0 + 32 + (size_t)64 * K, (char*)As[buf ^ 1] + w * 1024 + 4096);
            GLDS16(Wp + k0 + 32,                  (char*)Ws[buf ^ 1] + w * 1024);
        }
        short8 a[4], b[2];
#pragma unroll
        for (int m = 0; m < 4; ++m)
            a[m] = *(const short8*)(As[buf] + (wr + m * 16 + ro) * 32 + ge);
#pragma unroll
        for (int n = 0; n < 2; ++n)
            b[n] = *(const short8*)(Ws[buf] + (wc + n * 16 + ro) * 32 + ge);
#pragma unroll
        for (int m = 0; m < 4; ++m)
#pragma unroll
            for (int n = 0; n < 2; ++n)
                acc[m][n] = __builtin_amdgcn_mfma_f32_16x16x32_bf16(a[m], b[n], acc[m][n], 0, 0, 0);
        __syncthreads();
        buf ^= 1;
    }

    const int cr = (l >> 4) * 4;
#pragma unroll
    for (int m = 0; m < 4; ++m)
#pragma unroll
        for (int n = 0; n < 2; ++n)
#pragma unroll
            for (int j = 0; j < 4; ++j) {
                const int row = bm + wr + m * 16 + cr + j;
                const int col = bn + wc + n * 16 + ro;
                Cout[(size_t)row * N + col] = acc[m][n][j] + bias[col];
            }
}

__global__ __launch_bounds__(256)
void gemm_out(const u16* __restrict__ Ctx, const u16* __restrict__ wob,
              const float* __restrict__ bo, float* __restrict__ out)
{
    int lin = blockIdx.y * gridDim.x + blockIdx.x;
    const int cpx = (gridDim.x * gridDim.y) >> 3;
    lin = (lin & 7) * cpx + (lin >> 3);
    const int bx = lin % gridDim.x, by = lin / gridDim.x;
    gemm64_body(Ctx, wob, bo, out, D_MODEL, D_MODEL, bx, by);
}

// ---------------- bf16 MFMA flash attention, no-max softmax ----------------
// Q-block 64 rows, 4 waves (16 rows each), KV tile 64, double-buffered K/V.
// p = exp2(s) directly (Q pre-scaled by CSC); mask post-exp; l via ones-MFMA.
__global__ __launch_bounds__(256, 4)
void attn_mfma(const u16* __restrict__ Qp, const u16* __restrict__ Kp,
               const u16* __restrict__ Vt, const u64* __restrict__ mb,
               u16* __restrict__ Ctx)
{
    __shared__ char QsPs[8192];     // Q tile 64x128B; after hoist: per-wave P [16][128B]
    __shared__ char Ks[2][8192];
    __shared__ char Vs[2][8192];

    const int tid = threadIdx.x, l = tid & 63, w = tid >> 6;
    int lin = blockIdx.y * gridDim.x + blockIdx.x;
    lin = (lin & 7) * 128 + (lin >> 3);
    const int bx = lin & 31, by = lin >> 5;
    const int b = by >> 4, h = by & 15;
    const int q0 = bx * 64;
    const size_t tokbase = (size_t)b * SEQ;

    const int lrow = tid >> 3, ss = (tid & 7) ^ (lrow & 7);
    const u16* ksrc0 = Kp + (tokbase + lrow) * D_MODEL + h * 64 + ss * 8;
    const u16* vsrc0 = Vt + (size_t)(h * 64 + lrow) * M_ROWS + tokbase + ss * 8;

    {   // prologue: stage Q + first K/V tile
        const u16* qsrc = Qp + (tokbase + q0 + lrow) * D_MODEL + h * 64 + ss * 8;
        GLDS16(qsrc,                          QsPs + w * 1024);
        GLDS16(qsrc + (size_t)32 * D_MODEL,   QsPs + w * 1024 + 4096);
        GLDS16(ksrc0,                         (char*)Ks[0] + w * 1024);
        GLDS16(ksrc0 + (size_t)32 * D_MODEL,  (char*)Ks[0] + w * 1024 + 4096);
        GLDS16(vsrc0,                         (char*)Vs[0] + w * 1024);
        GLDS16(vsrc0 + (size_t)32 * M_ROWS,   (char*)Vs[0] + w * 1024 + 4096);
    }
    __syncthreads();

    const int ro = l & 15, gb = (l >> 4) * 16;

    short8 qf[2];
#pragma unroll
    for (int c = 0; c < 2; ++c) {
        const int row = w * 16 + ro;
        qf[c] = *(const short8*)(QsPs + row * 128 + ((c * 64 + gb) ^ ((row & 7) << 4)));
    }

    const uint2* mptr[4];
#pragma unroll
    for (int j = 0; j < 4; ++j)
        mptr[j] = (const uint2*)(mb + (tokbase + q0 + w * 16 + (l >> 4) * 4 + j) * (size_t)NT);

    f32x4 o[4], lacc = (f32x4)0.0f;
#pragma unroll
    for (int dn = 0; dn < 4; ++dn) o[dn] = (f32x4)0.0f;

    const short8 ones = {0x3F80, 0x3F80, 0x3F80, 0x3F80, 0x3F80, 0x3F80, 0x3F80, 0x3F80};

    uint2 mw[4];
#pragma unroll
    for (int j = 0; j < 4; ++j) mw[j] = mptr[j][0];

    for (int t = 0; t < NT; ++t) {
        const int cur = t & 1;

        uint2 mc[4];
#pragma unroll
        for (int j = 0; j < 4; ++j) mc[j] = mw[j];

        if (t + 1 < NT) {   // prefetch next K/V tile + mask words
            const u16* kn = ksrc0 + (size_t)(t + 1) * 64 * D_MODEL;
            const u16* vn = vsrc0 + (t + 1) * 64;
            GLDS16(kn,                         (char*)Ks[cur ^ 1] + w * 1024);
            GLDS16(kn + (size_t)32 * D_MODEL,  (char*)Ks[cur ^ 1] + w * 1024 + 4096);
            GLDS16(vn,                         (char*)Vs[cur ^ 1] + w * 1024);
            GLDS16(vn + (size_t)32 * M_ROWS,   (char*)Vs[cur ^ 1] + w * 1024 + 4096);
#pragma unroll
            for (int j = 0; j < 4; ++j) mw[j] = mptr[j][t + 1];
        }

        // ---- S = Q K^T (Q pre-scaled: s already in exp2 domain) ----
        f32x4 s[4];
#pragma unroll
        for (int n = 0; n < 4; ++n) {
            const int row = n * 16 + ro;
            short8 k0f = *(const short8*)(Ks[cur] + row * 128 + ((gb)      ^ ((row & 7) << 4)));
            short8 k1f = *(const short8*)(Ks[cur] + row * 128 + ((64 + gb) ^ ((row & 7) << 4)));
            f32x4 a = (f32x4)0.0f;
            a = __builtin_amdgcn_mfma_f32_16x16x32_bf16(qf[0], k0f, a, 0, 0, 0);
            a = __builtin_amdgcn_mfma_f32_16x16x32_bf16(qf[1], k1f, a, 0, 0, 0);
            s[n] = a;
        }

        // ---- P = exp2(S) * mask; pack bf16; write per-wave LDS ----
        char* pb = QsPs + w * 2048;
#pragma unroll
        for (int j = 0; j < 4; ++j) {
            const int prow = (l >> 4) * 4 + j;
            const int sw = (prow & 7) << 4;
            const unsigned wlo = mc[j].x >> ro;
            const unsigned whi = mc[j].y >> ro;
            float p0 = fexp2(s[0][j]); p0 = (wlo & 1u)       ? p0 : 0.f;
            float p1 = fexp2(s[1][j]); p1 = (wlo & 0x10000u) ? p1 : 0.f;
            float p2 = fexp2(s[2][j]); p2 = (whi & 1u)       ? p2 : 0.f;
            float p3 = fexp2(s[3][j]); p3 = (whi & 0x10000u) ? p3 : 0.f;
            unsigned pk01, pk23;
            asm("v_cvt_pk_bf16_f32 %0, %1, %2" : "=v"(pk01) : "v"(p0), "v"(p1));
            asm("v_cvt_pk_bf16_f32 %0, %1, %2" : "=v"(pk23) : "v"(p2), "v"(p3));
            *(u16*)(pb + prow * 128 + ((2 * (0  + ro)) ^ sw)) = (u16)pk01;
            *(u16*)(pb + prow * 128 + ((2 * (16 + ro)) ^ sw)) = (u16)(pk01 >> 16);
            *(u16*)(pb + prow * 128 + ((2 * (32 + ro)) ^ sw)) = (u16)pk23;
            *(u16*)(pb + prow * 128 + ((2 * (48 + ro)) ^ sw)) = (u16)(pk23 >> 16);
        }

        // ---- read P frags; l += P*1 (MFMA); O += P V ----
        short8 pf[2];
#pragma unroll
        for (int c = 0; c < 2; ++c)
            pf[c] = *(const short8*)(pb + ro * 128 + ((c * 64 + gb) ^ ((ro & 7) << 4)));

        lacc = __builtin_amdgcn_mfma_f32_16x16x32_bf16(pf[0], ones, lacc, 0, 0, 0);
        lacc = __builtin_amdgcn_mfma_f32_16x16x32_bf16(pf[1], ones, lacc, 0, 0, 0);

#pragma unroll
        for (int dn = 0; dn < 4; ++dn) {
            const int row = dn * 16 + ro;
            short8 v0f = *(const short8*)(Vs[cur] + row * 128 + ((gb)      ^ ((row & 7) << 4)));
            short8 v1f = *(const short8*)(Vs[cur] + row * 128 + ((64 + gb) ^ ((row & 7) << 4)));
            o[dn] = __builtin_amdgcn_mfma_f32_16x16x32_bf16(pf[0], v0f, o[dn], 0, 0, 0);
            o[dn] = __builtin_amdgcn_mfma_f32_16x16x32_bf16(pf[1], v1f, o[dn], 0, 0, 0);
        }

        __syncthreads();   // drains prefetch; protects buffer reuse
    }

    float inv[4];
#pragma unroll
    for (int j = 0; j < 4; ++j) inv[j] = 1.f / lacc[j];
#pragma unroll
    for (int dn = 0; dn < 4; ++dn)
#pragma unroll
        for (int j = 0; j < 4; ++j) {
            const size_t qr = tokbase + q0 + w * 16 + (l >> 4) * 4 + j;
            Ctx[qr * D_MODEL + h * 64 + dn * 16 + ro] = f2bf(o[dn][j] * inv[j]);
        }
}

extern "C" void kernel_launch(void* const* d_in, const int* in_sizes, int n_in,
                              void* d_out, int out_size, void* d_ws, size_t ws_size,
                              hipStream_t stream)
{
    const float* q    = (const float*)d_in[0];
    const float* k    = (const float*)d_in[1];
    const float* v    = (const float*)d_in[2];
    const int*   mask = (const int*)  d_in[3];
    const float* Wq   = (const float*)d_in[4];
    const float* bq   = (const float*)d_in[5];
    const float* Wk   = (const float*)d_in[6];
    const float* bk   = (const float*)d_in[7];
    const float* Wv   = (const float*)d_in[8];
    const float* bv   = (const float*)d_in[9];
    const float* Wo   = (const float*)d_in[10];
    const float* bo   = (const float*)d_in[11];
    float* out = (float*)d_out;

    u16* ws16 = (u16*)d_ws;
    const size_t M1 = 1024 * 1024;
    u16* qb  = ws16;               // 4M elems each
    u16* kb  = ws16 + 4 * M1;
    u16* vb  = ws16 + 8 * M1;
    u16* Wqb = ws16 + 12 * M1;     // 1M each
    u16* Wkb = ws16 + 13 * M1;
    u16* Wvb = ws16 + 14 * M1;
    u16* Wob = ws16 + 15 * M1;
    u16* Qp  = ws16 + 16 * M1;
    u16* Kp  = ws16 + 20 * M1;
    u16* Vt  = ws16 + 24 * M1;     // V^T [D_MODEL][M_ROWS]
    u16* Ctx = qb;                 // qb dead after gemm_proj
    u64* maskb = (u64*)vb;         // vb dead after gemm_proj

    cvt_all<<<2048, 256, 0, stream>>>(q, k, v, Wq, Wk, Wv, Wo,
                                      qb, kb, vb, Wqb, Wkb, Wvb, Wob);

    dim3 gproj(256, 3);
    gemm_proj<<<gproj, 256, 0, stream>>>(qb, kb, vb, Wqb, Wkb, Wvb, bq, bk, bv, Qp, Kp, Vt);

    mask_pack<<<1024, 256, 0, stream>>>(mask, maskb, BATCH * SEQ * SEQ / 64);

    dim3 ga(SEQ / 64, BATCH * N_HEAD);      // 1024 blocks
    attn_mfma<<<ga, 256, 0, stream>>>(Qp, Kp, Vt, maskb, Ctx);

    dim3 go(D_MODEL / 64, M_ROWS / 128);    // 512 blocks
    gemm_out<<<go, 256, 0, stream>>>(Ctx, Wob, bo, out);
}

// Round 5
// 295.266 us; speedup vs baseline: 5.0388x; 1.0366x over previous
//
#include <hip/hip_runtime.h>

#define D_MODEL 1024
#define N_HEAD  16
#define D_K     64
#define BATCH   2
#define SEQ     2048
#define M_ROWS  (BATCH*SEQ)
#define NT      (SEQ/64)

typedef __attribute__((ext_vector_type(8))) short short8;   // 8 bf16
typedef __attribute__((ext_vector_type(4))) float f32x4;
typedef unsigned short u16;
typedef unsigned long long u64;

#define GLDS16(g, l) \
    __builtin_amdgcn_global_load_lds((const __attribute__((address_space(1))) void*)(g), \
                                     (__attribute__((address_space(3))) void*)(l), 16, 0, 0)

// 1/sqrt(1024) * log2(e): folded into the Q projection output
#define CSC (0.03125f * 1.44269504089f)

__device__ __forceinline__ u16 f2bf(float f) {
    unsigned u = __builtin_bit_cast(unsigned, f);
    unsigned r = (u + 0x7fffu + ((u >> 16) & 1u)) >> 16;
    return (u16)r;
}

__device__ __forceinline__ float fexp2(float x) {
#if __has_builtin(__builtin_amdgcn_exp2f)
    return __builtin_amdgcn_exp2f(x);
#else
    return exp2f(x);
#endif
}

// ---------------- fused fp32->bf16 conversion + mask bit-pack ----------------
__global__ __launch_bounds__(256)
void cvt_and_mask(const float* __restrict__ q, const float* __restrict__ k, const float* __restrict__ v,
                  const float* __restrict__ wq, const float* __restrict__ wk,
                  const float* __restrict__ wv, const float* __restrict__ wo,
                  u16* __restrict__ qb, u16* __restrict__ kb, u16* __restrict__ vb,
                  u16* __restrict__ wqb, u16* __restrict__ wkb, u16* __restrict__ wvb,
                  u16* __restrict__ wob,
                  const int* __restrict__ mask, u64* __restrict__ mb)
{
    const int total = 3 * 1048576 + 4 * 262144;   // float4 units
    int i = blockIdx.x * blockDim.x + threadIdx.x;
    const int stride = gridDim.x * blockDim.x;
    for (; i < total; i += stride) {
        const float* src; u16* dst; int loc;
        if (i < 3 * 1048576) {
            const int t = i >> 20; loc = i & 1048575;
            src = (t == 0) ? q : (t == 1) ? k : v;
            dst = (t == 0) ? qb : (t == 1) ? kb : vb;
        } else {
            const int j = i - 3 * 1048576; const int t = j >> 18; loc = j & 262143;
            src = (t == 0) ? wq : (t == 1) ? wk : (t == 2) ? wv : wo;
            dst = (t == 0) ? wqb : (t == 1) ? wkb : (t == 2) ? wvb : wob;
        }
        float4 a = ((const float4*)src)[loc];
        ushort4 o;
        o.x = f2bf(a.x); o.y = f2bf(a.y); o.z = f2bf(a.z); o.w = f2bf(a.w);
        ((ushort4*)dst)[loc] = o;
    }

    // mask (int32 0/1) -> u64 bitmask per 64 cols
    const int lane = threadIdx.x & 63;
    int wd = (blockIdx.x * blockDim.x + threadIdx.x) >> 6;
    const int nw = (gridDim.x * blockDim.x) >> 6;
    for (; wd < BATCH * SEQ * SEQ / 64; wd += nw) {
        int mv = mask[(size_t)wd * 64 + lane];
        u64 bits = __ballot(mv != 0);
        if (lane == 0) mb[wd] = bits;
    }
}

// ---------------- 128x128 bf16 MFMA GEMM body (m97 structure, dbuf, 1 barrier/step) ----
// PERM: permute output cols within each 64-group: col' = 4*(c&15) + ((c&63)>>4)
// (the sigma-permutation consumed by attn's P/V k-ordering trick)
template<bool OUT_BF16, bool BIAS_ROW, bool SCALE, bool PERM>
__device__ __forceinline__
void gemm128_body(const u16* __restrict__ A, const u16* __restrict__ W,
                  const float* __restrict__ bias, void* __restrict__ Cout,
                  const int M, const int N, const int K, const int bx, const int by)
{
    __shared__ u16 As[2][128 * 32];
    __shared__ u16 Ws[2][128 * 32];
    const int tid = threadIdx.x, l = tid & 63, w = tid >> 6;
    const int bm = by * 128, bn = bx * 128;
    const int wr = (w >> 1) * 64, wc = (w & 1) * 64;
    const int srow = tid >> 2, scol = (tid & 3) * 8;
    const u16* Ap = A + (size_t)(bm + srow) * K + scol;
    const u16* Wp = W + (size_t)(bn + srow) * K + scol;

    f32x4 acc[4][4];
#pragma unroll
    for (int m = 0; m < 4; ++m)
#pragma unroll
        for (int n = 0; n < 4; ++n) acc[m][n] = (f32x4)0.0f;

    const int ro = l & 15, ge = (l >> 4) * 8;

    GLDS16(Ap,                  (char*)As[0] + w * 1024);
    GLDS16(Ap + (size_t)64 * K, (char*)As[0] + w * 1024 + 4096);
    GLDS16(Wp,                  (char*)Ws[0] + w * 1024);
    GLDS16(Wp + (size_t)64 * K, (char*)Ws[0] + w * 1024 + 4096);
    __syncthreads();

    int buf = 0;
    for (int k0 = 0; k0 < K; k0 += 32) {
        if (k0 + 32 < K) {
            GLDS16(Ap + k0 + 32,                  (char*)As[buf ^ 1] + w * 1024);
            GLDS16(Ap + k0 + 32 + (size_t)64 * K, (char*)As[buf ^ 1] + w * 1024 + 4096);
            GLDS16(Wp + k0 + 32,                  (char*)Ws[buf ^ 1] + w * 1024);
            GLDS16(Wp + k0 + 32 + (size_t)64 * K, (char*)Ws[buf ^ 1] + w * 1024 + 4096);
        }
        short8 a[4], b[4];
#pragma unroll
        for (int m = 0; m < 4; ++m)
            a[m] = *(const short8*)(As[buf] + (wr + m * 16 + ro) * 32 + ge);
#pragma unroll
        for (int n = 0; n < 4; ++n)
            b[n] = *(const short8*)(Ws[buf] + (wc + n * 16 + ro) * 32 + ge);
#pragma unroll
        for (int m = 0; m < 4; ++m)
#pragma unroll
            for (int n = 0; n < 4; ++n)
                acc[m][n] = __builtin_amdgcn_mfma_f32_16x16x32_bf16(a[m], b[n], acc[m][n], 0, 0, 0);
        __syncthreads();
        buf ^= 1;
    }

    const int cr = (l >> 4) * 4;
#pragma unroll
    for (int m = 0; m < 4; ++m)
#pragma unroll
        for (int n = 0; n < 4; ++n)
#pragma unroll
            for (int j = 0; j < 4; ++j) {
                const int row = bm + wr + m * 16 + cr + j;
                const int col = bn + wc + n * 16 + ro;
                float vvv = acc[m][n][j] + (BIAS_ROW ? bias[row] : bias[col]);
                if constexpr (SCALE) vvv *= CSC;
                int colst = col;
                if constexpr (PERM) colst = bn + wc + 4 * ro + n;   // sigma^-1 within 64-group
                if constexpr (OUT_BF16)
                    ((u16*)Cout)[(size_t)row * N + colst] = f2bf(vvv);
                else
                    ((float*)Cout)[(size_t)row * N + colst] = vvv;
            }
}

// fused Q,K,V^T projections: grid (256, 3)
__global__ __launch_bounds__(256)
void gemm_proj(const u16* __restrict__ qb, const u16* __restrict__ kb, const u16* __restrict__ vb,
               const u16* __restrict__ wqb, const u16* __restrict__ wkb, const u16* __restrict__ wvb,
               const float* __restrict__ bq, const float* __restrict__ bk, const float* __restrict__ bv,
               u16* __restrict__ Qp, u16* __restrict__ Kp, u16* __restrict__ Vt)
{
    int lin = blockIdx.x;
    lin = (lin & 7) * 32 + (lin >> 3);   // XCD-chunked
    const int z = blockIdx.y;
    if (z == 0)       // Q projection, pre-scaled by CSC
        gemm128_body<true, false, true,  false>(qb, wqb, bq, Qp, M_ROWS, D_MODEL, D_MODEL, lin & 7, lin >> 3);
    else if (z == 1)  // K projection
        gemm128_body<true, false, false, false>(kb, wkb, bk, Kp, M_ROWS, D_MODEL, D_MODEL, lin & 7, lin >> 3);
    else              // V^T = Wv @ v^T  (bias per row), token-permuted per 64-group
        gemm128_body<true, true,  false, true >(wvb, vb, bv, Vt, D_MODEL, M_ROWS, D_MODEL, lin & 31, lin >> 5);
}

// ---------------- 128x64 GEMM for the output projection (512 blocks) ----------------
__device__ __forceinline__
void gemm64_body(const u16* __restrict__ A, const u16* __restrict__ W,
                 const float* __restrict__ bias, float* __restrict__ Cout,
                 const int N, const int K, const int bx, const int by)
{
    __shared__ u16 As[2][128 * 32];
    __shared__ u16 Ws[2][64 * 32];
    const int tid = threadIdx.x, l = tid & 63, w = tid >> 6;
    const int bm = by * 128, bn = bx * 64;
    const int wr = (w >> 1) * 64, wc = (w & 1) * 32;
    const int srow = tid >> 2, scol = (tid & 3) * 8;
    const u16* Ap = A + (size_t)(bm + srow) * K + scol;
    const u16* Wp = W + (size_t)(bn + srow) * K + scol;

    f32x4 acc[4][2];
#pragma unroll
    for (int m = 0; m < 4; ++m)
#pragma unroll
        for (int n = 0; n < 2; ++n) acc[m][n] = (f32x4)0.0f;

    const int ro = l & 15, ge = (l >> 4) * 8;

    GLDS16(Ap,                  (char*)As[0] + w * 1024);
    GLDS16(Ap + (size_t)64 * K, (char*)As[0] + w * 1024 + 4096);
    GLDS16(Wp,                  (char*)Ws[0] + w * 1024);
    __syncthreads();

    int buf = 0;
    for (int k0 = 0; k0 < K; k0 += 32) {
        if (k0 + 32 < K) {
            GLDS16(Ap + k0 + 32,                  (char*)As[buf ^ 1] + w * 1024);
            GLDS16(Ap + k0 + 32 + (size_t)64 * K, (char*)As[buf ^ 1] + w * 1024 + 4096);
            GLDS16(Wp + k0 + 32,                  (char*)Ws[buf ^ 1] + w * 1024);
        }
        short8 a[4], b[2];
#pragma unroll
        for (int m = 0; m < 4; ++m)
            a[m] = *(const short8*)(As[buf] + (wr + m * 16 + ro) * 32 + ge);
#pragma unroll
        for (int n = 0; n < 2; ++n)
            b[n] = *(const short8*)(Ws[buf] + (wc + n * 16 + ro) * 32 + ge);
#pragma unroll
        for (int m = 0; m < 4; ++m)
#pragma unroll
            for (int n = 0; n < 2; ++n)
                acc[m][n] = __builtin_amdgcn_mfma_f32_16x16x32_bf16(a[m], b[n], acc[m][n], 0, 0, 0);
        __syncthreads();
        buf ^= 1;
    }

    const int cr = (l >> 4) * 4;
#pragma unroll
    for (int m = 0; m < 4; ++m)
#pragma unroll
        for (int n = 0; n < 2; ++n)
#pragma unroll
            for (int j = 0; j < 4; ++j) {
                const int row = bm + wr + m * 16 + cr + j;
                const int col = bn + wc + n * 16 + ro;
                Cout[(size_t)row * N + col] = acc[m][n][j] + bias[col];
            }
}

__global__ __launch_bounds__(256)
void gemm_out(const u16* __restrict__ Ctx, const u16* __restrict__ wob,
              const float* __restrict__ bo, float* __restrict__ out)
{
    int lin = blockIdx.y * gridDim.x + blockIdx.x;
    const int cpx = (gridDim.x * gridDim.y) >> 3;
    lin = (lin & 7) * cpx + (lin >> 3);
    const int bx = lin % gridDim.x, by = lin / gridDim.x;
    gemm64_body(Ctx, wob, bo, out, D_MODEL, D_MODEL, bx, by);
}

// ---------------- bf16 MFMA flash attention, no-max softmax ----------------
// Q-block 128 rows, 4 waves x 32 rows; KV tile 64, double-buffered.
// P written as ds_write_b64 under k-permutation sigma (V^T pre-permuted in global).
__global__ __launch_bounds__(256, 2)
void attn_mfma(const u16* __restrict__ Qp, const u16* __restrict__ Kp,
               const u16* __restrict__ Vt, const u64* __restrict__ mb,
               u16* __restrict__ Ctx)
{
    __shared__ char QsPs[16384];    // Q 128x128B; after hoist: per-wave P [32][128B] at w*4096
    __shared__ char Ks[2][8192];    // [64 kcol][64 d]
    __shared__ char Vs[2][8192];    // V^T [64 d][64 kcol-permuted]

    const int tid = threadIdx.x, l = tid & 63, w = tid >> 6;
    int lin = blockIdx.y * gridDim.x + blockIdx.x;   // 512 wgs
    lin = (lin & 7) * 64 + (lin >> 3);
    const int bx = lin & 15, by = lin >> 4;
    const int b = by >> 4, h = by & 15;
    const int q0 = bx * 128;
    const size_t tokbase = (size_t)b * SEQ;

    const int lrow = tid >> 3, ss = (tid & 7) ^ (lrow & 7);
    const u16* ksrc0 = Kp + (tokbase + lrow) * D_MODEL + h * 64 + ss * 8;
    const u16* vsrc0 = Vt + (size_t)(h * 64 + lrow) * M_ROWS + tokbase + ss * 8;

    {   // prologue: stage Q (16KB, 4 issues) + first K/V tile
        const u16* qsrc = Qp + (tokbase + q0 + lrow) * D_MODEL + h * 64 + ss * 8;
#pragma unroll
        for (int i = 0; i < 4; ++i)
            GLDS16(qsrc + (size_t)32 * i * D_MODEL, QsPs + w * 1024 + i * 4096);
        GLDS16(ksrc0,                        (char*)Ks[0] + w * 1024);
        GLDS16(ksrc0 + (size_t)32 * D_MODEL, (char*)Ks[0] + w * 1024 + 4096);
        GLDS16(vsrc0,                        (char*)Vs[0] + w * 1024);
        GLDS16(vsrc0 + (size_t)32 * M_ROWS,  (char*)Vs[0] + w * 1024 + 4096);
    }
    __syncthreads();

    const int ro = l & 15, g = l >> 4, gb = g * 16;

    // hoist Q fragments: wave reads only its own 32 rows (its own future P region)
    short8 qf[2][2];
#pragma unroll
    for (int mi = 0; mi < 2; ++mi)
#pragma unroll
        for (int c = 0; c < 2; ++c) {
            const int row = w * 32 + mi * 16 + ro;
            qf[mi][c] = *(const short8*)(QsPs + row * 128 + ((c * 64 + gb) ^ ((row & 7) << 4)));
        }

    int mrow[2][4];
#pragma unroll
    for (int mi = 0; mi < 2; ++mi)
#pragma unroll
        for (int j = 0; j < 4; ++j)
            mrow[mi][j] = (int)((tokbase + q0 + w * 32 + mi * 16 + g * 4 + j) * NT);

    f32x4 o[2][4], lacc[2];
#pragma unroll
    for (int mi = 0; mi < 2; ++mi) {
        lacc[mi] = (f32x4)0.0f;
#pragma unroll
        for (int dn = 0; dn < 4; ++dn) o[mi][dn] = (f32x4)0.0f;
    }

    const short8 ones = {0x3F80, 0x3F80, 0x3F80, 0x3F80, 0x3F80, 0x3F80, 0x3F80, 0x3F80};

    for (int t = 0; t < NT; ++t) {
        const int cur = t & 1;

        u64 mw[2][4];
#pragma unroll
        for (int mi = 0; mi < 2; ++mi)
#pragma unroll
            for (int j = 0; j < 4; ++j) mw[mi][j] = mb[mrow[mi][j] + t];

        if (t + 1 < NT) {   // prefetch next K/V tile into the other buffer
            const u16* kn = ksrc0 + (size_t)(t + 1) * 64 * D_MODEL;
            const u16* vn = vsrc0 + (t + 1) * 64;
            GLDS16(kn,                         (char*)Ks[cur ^ 1] + w * 1024);
            GLDS16(kn + (size_t)32 * D_MODEL,  (char*)Ks[cur ^ 1] + w * 1024 + 4096);
            GLDS16(vn,                         (char*)Vs[cur ^ 1] + w * 1024);
            GLDS16(vn + (size_t)32 * M_ROWS,   (char*)Vs[cur ^ 1] + w * 1024 + 4096);
        }

        // ---- S = Q K^T (pre-scaled into exp2 domain) ----
        f32x4 s[2][4];
#pragma unroll
        for (int n = 0; n < 4; ++n) {
            const int row = n * 16 + ro;
            const int sw = (row & 7) << 4;
            short8 k0f = *(const short8*)(Ks[cur] + row * 128 + (gb ^ sw));
            short8 k1f = *(const short8*)(Ks[cur] + row * 128 + ((64 + gb) ^ sw));
#pragma unroll
            for (int mi = 0; mi < 2; ++mi) {
                f32x4 a = (f32x4)0.0f;
                a = __builtin_amdgcn_mfma_f32_16x16x32_bf16(qf[mi][0], k0f, a, 0, 0, 0);
                a = __builtin_amdgcn_mfma_f32_16x16x32_bf16(qf[mi][1], k1f, a, 0, 0, 0);
                s[mi][n] = a;
            }
        }

        // ---- P = exp2(S)*mask; pack; ONE b64 write per row (sigma ordering) ----
#pragma unroll
        for (int mi = 0; mi < 2; ++mi) {
            char* pb = QsPs + w * 4096 + mi * 2048;
#pragma unroll
            for (int j = 0; j < 4; ++j) {
                const int prow = g * 4 + j;
                const unsigned wlo = (unsigned)(mw[mi][j]) >> ro;
                const unsigned whi = (unsigned)(mw[mi][j] >> 32) >> ro;
                float p0 = fexp2(s[mi][0][j]); p0 = (wlo & 1u)       ? p0 : 0.f;
                float p1 = fexp2(s[mi][1][j]); p1 = (wlo & 0x10000u) ? p1 : 0.f;
                float p2 = fexp2(s[mi][2][j]); p2 = (whi & 1u)       ? p2 : 0.f;
                float p3 = fexp2(s[mi][3][j]); p3 = (whi & 0x10000u) ? p3 : 0.f;
                unsigned pk01, pk23;
                asm("v_cvt_pk_bf16_f32 %0, %1, %2" : "=v"(pk01) : "v"(p0), "v"(p1));
                asm("v_cvt_pk_bf16_f32 %0, %1, %2" : "=v"(pk23) : "v"(p2), "v"(p3));
                const u64 pv = (u64)pk01 | ((u64)pk23 << 32);
                *(u64*)(pb + prow * 128 + ((8 * ro) ^ ((prow & 7) << 4))) = pv;
            }
        }

        // ---- P A-frags; l += P*1 (MFMA); O += P V ----
        short8 pf[2][2];
#pragma unroll
        for (int mi = 0; mi < 2; ++mi)
#pragma unroll
            for (int c = 0; c < 2; ++c) {
                const int row = mi * 16 + ro;
                pf[mi][c] = *(const short8*)(QsPs + w * 4096 + row * 128 +
                                             ((c * 64 + gb) ^ ((ro & 7) << 4)));
            }

#pragma unroll
        for (int mi = 0; mi < 2; ++mi) {
            lacc[mi] = __builtin_amdgcn_mfma_f32_16x16x32_bf16(pf[mi][0], ones, lacc[mi], 0, 0, 0);
            lacc[mi] = __builtin_amdgcn_mfma_f32_16x16x32_bf16(pf[mi][1], ones, lacc[mi], 0, 0, 0);
        }

#pragma unroll
        for (int dn = 0; dn < 4; ++dn) {
            const int row = dn * 16 + ro;
            const int sw = (row & 7) << 4;
            short8 v0f = *(const short8*)(Vs[cur] + row * 128 + (gb ^ sw));
            short8 v1f = *(const short8*)(Vs[cur] + row * 128 + ((64 + gb) ^ sw));
#pragma unroll
            for (int mi = 0; mi < 2; ++mi) {
                o[mi][dn] = __builtin_amdgcn_mfma_f32_16x16x32_bf16(pf[mi][0], v0f, o[mi][dn], 0, 0, 0);
                o[mi][dn] = __builtin_amdgcn_mfma_f32_16x16x32_bf16(pf[mi][1], v1f, o[mi][dn], 0, 0, 0);
            }
        }

        __syncthreads();   // drains prefetch; protects buffer reuse
    }

    // ---- normalize + write ctx (bf16, [B*S][D_MODEL]) ----
#pragma unroll
    for (int mi = 0; mi < 2; ++mi) {
        float inv[4];
#pragma unroll
        for (int j = 0; j < 4; ++j) inv[j] = 1.f / lacc[mi][j];
#pragma unroll
        for (int dn = 0; dn < 4; ++dn)
#pragma unroll
            for (int j = 0; j < 4; ++j) {
                const size_t qr = tokbase + q0 + w * 32 + mi * 16 + g * 4 + j;
                Ctx[qr * D_MODEL + h * 64 + dn * 16 + ro] = f2bf(o[mi][dn][j] * inv[j]);
            }
    }
}

extern "C" void kernel_launch(void* const* d_in, const int* in_sizes, int n_in,
                              void* d_out, int out_size, void* d_ws, size_t ws_size,
                              hipStream_t stream)
{
    const float* q    = (const float*)d_in[0];
    const float* k    = (const float*)d_in[1];
    const float* v    = (const float*)d_in[2];
    const int*   mask = (const int*)  d_in[3];
    const float* Wq   = (const float*)d_in[4];
    const float* bq   = (const float*)d_in[5];
    const float* Wk   = (const float*)d_in[6];
    const float* bk   = (const float*)d_in[7];
    const float* Wv   = (const float*)d_in[8];
    const float* bv   = (const float*)d_in[9];
    const float* Wo   = (const float*)d_in[10];
    const float* bo   = (const float*)d_in[11];
    float* out = (float*)d_out;

    u16* ws16 = (u16*)d_ws;
    const size_t M1 = 1024 * 1024;
    u16* qb  = ws16;               // 4M elems each
    u16* kb  = ws16 + 4 * M1;
    u16* vb  = ws16 + 8 * M1;
    u16* Wqb = ws16 + 12 * M1;     // 1M each
    u16* Wkb = ws16 + 13 * M1;
    u16* Wvb = ws16 + 14 * M1;
    u16* Wob = ws16 + 15 * M1;
    u16* Qp  = ws16 + 16 * M1;
    u16* Kp  = ws16 + 20 * M1;
    u16* Vt  = ws16 + 24 * M1;     // V^T [D_MODEL][M_ROWS], token-permuted per 64-group
    u64* maskb = (u64*)(ws16 + 28 * M1);   // 1 MB
    u16* Ctx = qb;                 // qb dead after gemm_proj

    cvt_and_mask<<<2048, 256, 0, stream>>>(q, k, v, Wq, Wk, Wv, Wo,
                                           qb, kb, vb, Wqb, Wkb, Wvb, Wob,
                                           mask, maskb);

    dim3 gproj(256, 3);
    gemm_proj<<<gproj, 256, 0, stream>>>(qb, kb, vb, Wqb, Wkb, Wvb, bq, bk, bv, Qp, Kp, Vt);

    dim3 ga(SEQ / 128, BATCH * N_HEAD);     // (16, 32) = 512 blocks
    attn_mfma<<<ga, 256, 0, stream>>>(Qp, Kp, Vt, maskb, Ctx);

    dim3 go(D_MODEL / 64, M_ROWS / 128);    // 512 blocks
    gemm_out<<<go, 256, 0, stream>>>(Ctx, Wob, bo, out);
}

// Round 6
// 282.882 us; speedup vs baseline: 5.2594x; 1.0438x over previous
//
#include <hip/hip_runtime.h>

#define D_MODEL 1024
#define N_HEAD  16
#define D_K     64
#define BATCH   2
#define SEQ     2048
#define M_ROWS  (BATCH*SEQ)
#define NT      (SEQ/64)

typedef __attribute__((ext_vector_type(8))) short short8;   // 8 bf16
typedef __attribute__((ext_vector_type(4))) float f32x4;
typedef unsigned short u16;
typedef unsigned long long u64;

#define GLDS16(g, l) \
    __builtin_amdgcn_global_load_lds((const __attribute__((address_space(1))) void*)(g), \
                                     (__attribute__((address_space(3))) void*)(l), 16, 0, 0)

// 1/sqrt(1024) * log2(e): folded into the Q projection output
#define CSC (0.03125f * 1.44269504089f)

__device__ __forceinline__ u16 f2bf(float f) {
    unsigned u = __builtin_bit_cast(unsigned, f);
    unsigned r = (u + 0x7fffu + ((u >> 16) & 1u)) >> 16;
    return (u16)r;
}

__device__ __forceinline__ float fexp2(float x) {
#if __has_builtin(__builtin_amdgcn_exp2f)
    return __builtin_amdgcn_exp2f(x);
#else
    return exp2f(x);
#endif
}

// ---------------- fused fp32->bf16 conversion + mask bit-pack ----------------
__global__ __launch_bounds__(256)
void cvt_and_mask(const float* __restrict__ q, const float* __restrict__ k, const float* __restrict__ v,
                  const float* __restrict__ wq, const float* __restrict__ wk,
                  const float* __restrict__ wv, const float* __restrict__ wo,
                  u16* __restrict__ qb, u16* __restrict__ kb, u16* __restrict__ vb,
                  u16* __restrict__ wqb, u16* __restrict__ wkb, u16* __restrict__ wvb,
                  u16* __restrict__ wob,
                  const int* __restrict__ mask, u64* __restrict__ mb)
{
    const int total = 3 * 1048576 + 4 * 262144;   // float4 units
    int i = blockIdx.x * blockDim.x + threadIdx.x;
    const int stride = gridDim.x * blockDim.x;
    for (; i < total; i += stride) {
        const float* src; u16* dst; int loc;
        if (i < 3 * 1048576) {
            const int t = i >> 20; loc = i & 1048575;
            src = (t == 0) ? q : (t == 1) ? k : v;
            dst = (t == 0) ? qb : (t == 1) ? kb : vb;
        } else {
            const int j = i - 3 * 1048576; const int t = j >> 18; loc = j & 262143;
            src = (t == 0) ? wq : (t == 1) ? wk : (t == 2) ? wv : wo;
            dst = (t == 0) ? wqb : (t == 1) ? wkb : (t == 2) ? wvb : wob;
        }
        float4 a = ((const float4*)src)[loc];
        ushort4 o;
        o.x = f2bf(a.x); o.y = f2bf(a.y); o.z = f2bf(a.z); o.w = f2bf(a.w);
        ((ushort4*)dst)[loc] = o;
    }

    // mask (int32 0/1) -> u64 bitmask per 64 cols
    const int lane = threadIdx.x & 63;
    int wd = (blockIdx.x * blockDim.x + threadIdx.x) >> 6;
    const int nw = (gridDim.x * blockDim.x) >> 6;
    for (; wd < BATCH * SEQ * SEQ / 64; wd += nw) {
        int mv = mask[(size_t)wd * 64 + lane];
        u64 bits = __ballot(mv != 0);
        if (lane == 0) mb[wd] = bits;
    }
}

// ---------------- 128x128 bf16 MFMA GEMM body (m97 structure, dbuf, 1 barrier/step) ----
// PERM: write output cols in sigma-order within each 64-group (consumed by attn's
// in-register P/V k-slot mapping): token k_local=n*16+ro stored at position
// p = (n>>1)*32 + (ro>>2)*8 + (n&1)*4 + (ro&3).
template<bool OUT_BF16, bool BIAS_ROW, bool SCALE, bool PERM>
__device__ __forceinline__
void gemm128_body(const u16* __restrict__ A, const u16* __restrict__ W,
                  const float* __restrict__ bias, void* __restrict__ Cout,
                  const int M, const int N, const int K, const int bx, const int by)
{
    __shared__ u16 As[2][128 * 32];
    __shared__ u16 Ws[2][128 * 32];
    const int tid = threadIdx.x, l = tid & 63, w = tid >> 6;
    const int bm = by * 128, bn = bx * 128;
    const int wr = (w >> 1) * 64, wc = (w & 1) * 64;
    const int srow = tid >> 2, scol = (tid & 3) * 8;
    const u16* Ap = A + (size_t)(bm + srow) * K + scol;
    const u16* Wp = W + (size_t)(bn + srow) * K + scol;

    f32x4 acc[4][4];
#pragma unroll
    for (int m = 0; m < 4; ++m)
#pragma unroll
        for (int n = 0; n < 4; ++n) acc[m][n] = (f32x4)0.0f;

    const int ro = l & 15, ge = (l >> 4) * 8;

    GLDS16(Ap,                  (char*)As[0] + w * 1024);
    GLDS16(Ap + (size_t)64 * K, (char*)As[0] + w * 1024 + 4096);
    GLDS16(Wp,                  (char*)Ws[0] + w * 1024);
    GLDS16(Wp + (size_t)64 * K, (char*)Ws[0] + w * 1024 + 4096);
    __syncthreads();

    int buf = 0;
    for (int k0 = 0; k0 < K; k0 += 32) {
        if (k0 + 32 < K) {
            GLDS16(Ap + k0 + 32,                  (char*)As[buf ^ 1] + w * 1024);
            GLDS16(Ap + k0 + 32 + (size_t)64 * K, (char*)As[buf ^ 1] + w * 1024 + 4096);
            GLDS16(Wp + k0 + 32,                  (char*)Ws[buf ^ 1] + w * 1024);
            GLDS16(Wp + k0 + 32 + (size_t)64 * K, (char*)Ws[buf ^ 1] + w * 1024 + 4096);
        }
        short8 a[4], b[4];
#pragma unroll
        for (int m = 0; m < 4; ++m)
            a[m] = *(const short8*)(As[buf] + (wr + m * 16 + ro) * 32 + ge);
#pragma unroll
        for (int n = 0; n < 4; ++n)
            b[n] = *(const short8*)(Ws[buf] + (wc + n * 16 + ro) * 32 + ge);
#pragma unroll
        for (int m = 0; m < 4; ++m)
#pragma unroll
            for (int n = 0; n < 4; ++n)
                acc[m][n] = __builtin_amdgcn_mfma_f32_16x16x32_bf16(a[m], b[n], acc[m][n], 0, 0, 0);
        __syncthreads();
        buf ^= 1;
    }

    const int cr = (l >> 4) * 4;
#pragma unroll
    for (int m = 0; m < 4; ++m)
#pragma unroll
        for (int n = 0; n < 4; ++n)
#pragma unroll
            for (int j = 0; j < 4; ++j) {
                const int row = bm + wr + m * 16 + cr + j;
                const int col = bn + wc + n * 16 + ro;
                float vvv = acc[m][n][j] + (BIAS_ROW ? bias[row] : bias[col]);
                if constexpr (SCALE) vvv *= CSC;
                int colst = col;
                if constexpr (PERM)
                    colst = bn + wc + (n >> 1) * 32 + (ro >> 2) * 8 + (n & 1) * 4 + (ro & 3);
                if constexpr (OUT_BF16)
                    ((u16*)Cout)[(size_t)row * N + colst] = f2bf(vvv);
                else
                    ((float*)Cout)[(size_t)row * N + colst] = vvv;
            }
}

// fused Q,K,V^T projections: grid (256, 3)
__global__ __launch_bounds__(256)
void gemm_proj(const u16* __restrict__ qb, const u16* __restrict__ kb, const u16* __restrict__ vb,
               const u16* __restrict__ wqb, const u16* __restrict__ wkb, const u16* __restrict__ wvb,
               const float* __restrict__ bq, const float* __restrict__ bk, const float* __restrict__ bv,
               u16* __restrict__ Qp, u16* __restrict__ Kp, u16* __restrict__ Vt)
{
    int lin = blockIdx.x;
    lin = (lin & 7) * 32 + (lin >> 3);   // XCD-chunked
    const int z = blockIdx.y;
    if (z == 0)       // Q projection, pre-scaled by CSC
        gemm128_body<true, false, true,  false>(qb, wqb, bq, Qp, M_ROWS, D_MODEL, D_MODEL, lin & 7, lin >> 3);
    else if (z == 1)  // K projection
        gemm128_body<true, false, false, false>(kb, wkb, bk, Kp, M_ROWS, D_MODEL, D_MODEL, lin & 7, lin >> 3);
    else              // V^T = Wv @ v^T  (bias per row), sigma-permuted per 64-token group
        gemm128_body<true, true,  false, true >(wvb, vb, bv, Vt, D_MODEL, M_ROWS, D_MODEL, lin & 31, lin >> 5);
}

// ---------------- 128x64 GEMM for the output projection (512 blocks) ----------------
__device__ __forceinline__
void gemm64_body(const u16* __restrict__ A, const u16* __restrict__ W,
                 const float* __restrict__ bias, float* __restrict__ Cout,
                 const int N, const int K, const int bx, const int by)
{
    __shared__ u16 As[2][128 * 32];
    __shared__ u16 Ws[2][64 * 32];
    const int tid = threadIdx.x, l = tid & 63, w = tid >> 6;
    const int bm = by * 128, bn = bx * 64;
    const int wr = (w >> 1) * 64, wc = (w & 1) * 32;
    const int srow = tid >> 2, scol = (tid & 3) * 8;
    const u16* Ap = A + (size_t)(bm + srow) * K + scol;
    const u16* Wp = W + (size_t)(bn + srow) * K + scol;

    f32x4 acc[4][2];
#pragma unroll
    for (int m = 0; m < 4; ++m)
#pragma unroll
        for (int n = 0; n < 2; ++n) acc[m][n] = (f32x4)0.0f;

    const int ro = l & 15, ge = (l >> 4) * 8;

    GLDS16(Ap,                  (char*)As[0] + w * 1024);
    GLDS16(Ap + (size_t)64 * K, (char*)As[0] + w * 1024 + 4096);
    GLDS16(Wp,                  (char*)Ws[0] + w * 1024);
    __syncthreads();

    int buf = 0;
    for (int k0 = 0; k0 < K; k0 += 32) {
        if (k0 + 32 < K) {
            GLDS16(Ap + k0 + 32,                  (char*)As[buf ^ 1] + w * 1024);
            GLDS16(Ap + k0 + 32 + (size_t)64 * K, (char*)As[buf ^ 1] + w * 1024 + 4096);
            GLDS16(Wp + k0 + 32,                  (char*)Ws[buf ^ 1] + w * 1024);
        }
        short8 a[4], b[2];
#pragma unroll
        for (int m = 0; m < 4; ++m)
            a[m] = *(const short8*)(As[buf] + (wr + m * 16 + ro) * 32 + ge);
#pragma unroll
        for (int n = 0; n < 2; ++n)
            b[n] = *(const short8*)(Ws[buf] + (wc + n * 16 + ro) * 32 + ge);
#pragma unroll
        for (int m = 0; m < 4; ++m)
#pragma unroll
            for (int n = 0; n < 2; ++n)
                acc[m][n] = __builtin_amdgcn_mfma_f32_16x16x32_bf16(a[m], b[n], acc[m][n], 0, 0, 0);
        __syncthreads();
        buf ^= 1;
    }

    const int cr = (l >> 4) * 4;
#pragma unroll
    for (int m = 0; m < 4; ++m)
#pragma unroll
        for (int n = 0; n < 2; ++n)
#pragma unroll
            for (int j = 0; j < 4; ++j) {
                const int row = bm + wr + m * 16 + cr + j;
                const int col = bn + wc + n * 16 + ro;
                Cout[(size_t)row * N + col] = acc[m][n][j] + bias[col];
            }
}

__global__ __launch_bounds__(256)
void gemm_out(const u16* __restrict__ Ctx, const u16* __restrict__ wob,
              const float* __restrict__ bo, float* __restrict__ out)
{
    int lin = blockIdx.y * gridDim.x + blockIdx.x;
    const int cpx = (gridDim.x * gridDim.y) >> 3;
    lin = (lin & 7) * cpx + (lin >> 3);
    const int bx = lin % gridDim.x, by = lin / gridDim.x;
    gemm64_body(Ctx, wob, bo, out, D_MODEL, D_MODEL, bx, by);
}

// ---------------- bf16 MFMA flash attention: swapped QK^T, P fully in-register ----
// Q-block 128 rows, 4 waves x 32 rows; KV tile 64, double-buffered K/V (32KB LDS).
// S^T = mfma(K,Q) puts each q-row's scores lane-local; sigma k-slot mapping makes
// the PV A-fragment = the lane's own values (V^T pre-permuted by gemm_proj).
__global__ __launch_bounds__(256, 4)
void attn_mfma(const u16* __restrict__ Qp, const u16* __restrict__ Kp,
               const u16* __restrict__ Vt, const u64* __restrict__ mb,
               u16* __restrict__ Ctx)
{
    __shared__ char Ks[2][8192];    // [64 kcol][64 d * 2B]
    __shared__ char Vs[2][8192];    // V^T [64 d][64 sigma-ordered kcol]

    const int tid = threadIdx.x, l = tid & 63, w = tid >> 6;
    int lin = blockIdx.y * gridDim.x + blockIdx.x;   // 512 wgs
    lin = (lin & 7) * 64 + (lin >> 3);
    const int bx = lin & 15, by = lin >> 4;
    const int b = by >> 4, h = by & 15;
    const int q0 = bx * 128;
    const size_t tokbase = (size_t)b * SEQ;

    const int lrow = tid >> 3, ss = (tid & 7) ^ (lrow & 7);
    const u16* ksrc0 = Kp + (tokbase + lrow) * D_MODEL + h * 64 + ss * 8;
    const u16* vsrc0 = Vt + (size_t)(h * 64 + lrow) * M_ROWS + tokbase + ss * 8;

    // stage first K/V tile
    GLDS16(ksrc0,                        (char*)Ks[0] + w * 1024);
    GLDS16(ksrc0 + (size_t)32 * D_MODEL, (char*)Ks[0] + w * 1024 + 4096);
    GLDS16(vsrc0,                        (char*)Vs[0] + w * 1024);
    GLDS16(vsrc0 + (size_t)32 * M_ROWS,  (char*)Vs[0] + w * 1024 + 4096);

    const int ro = l & 15, g = l >> 4;
    const int gb = g * 16, g4 = g * 4;

    // Q fragments direct from global: lane (g,ro) <- Q[qrow=mi*16+ro][d = dc*32+8g..+8]
    short8 qf[2][2];
    {
        const u16* qr = Qp + (tokbase + q0 + w * 32 + ro) * (size_t)D_MODEL + h * 64 + 8 * g;
        qf[0][0] = *(const short8*)(qr);
        qf[0][1] = *(const short8*)(qr + 32);
        qf[1][0] = *(const short8*)(qr + (size_t)16 * D_MODEL);
        qf[1][1] = *(const short8*)(qr + (size_t)16 * D_MODEL + 32);
    }

    // mask words: lane (g,ro) needs the word for its q-rows (mi*16+ro)
    const u64* mr0 = mb + (tokbase + q0 + w * 32 + ro) * (size_t)NT;
    const u64* mr1 = mr0 + (size_t)16 * NT;
    u64 mw0 = mr0[0], mw1 = mr1[0];

    f32x4 o[2][4], lacc[2];
#pragma unroll
    for (int mi = 0; mi < 2; ++mi) {
        lacc[mi] = (f32x4)0.0f;
#pragma unroll
        for (int dn = 0; dn < 4; ++dn) o[mi][dn] = (f32x4)0.0f;
    }
    const short8 ones = {0x3F80, 0x3F80, 0x3F80, 0x3F80, 0x3F80, 0x3F80, 0x3F80, 0x3F80};

    __syncthreads();

    for (int t = 0; t < NT; ++t) {
        const int cur = t & 1;
        const u64 mc0 = mw0, mc1 = mw1;

        if (t + 1 < NT) {   // prefetch next K/V tile + next mask words
            const u16* kn = ksrc0 + (size_t)(t + 1) * 64 * D_MODEL;
            const u16* vn = vsrc0 + (t + 1) * 64;
            GLDS16(kn,                         (char*)Ks[cur ^ 1] + w * 1024);
            GLDS16(kn + (size_t)32 * D_MODEL,  (char*)Ks[cur ^ 1] + w * 1024 + 4096);
            GLDS16(vn,                         (char*)Vs[cur ^ 1] + w * 1024);
            GLDS16(vn + (size_t)32 * M_ROWS,   (char*)Vs[cur ^ 1] + w * 1024 + 4096);
            mw0 = mr0[t + 1]; mw1 = mr1[t + 1];
        }

        // ---- S^T = K Q^T per kcol-chunk; mask+exp2+pack in-lane -> pf ----
        short8 pf[2][2];
#pragma unroll
        for (int kc = 0; kc < 2; ++kc) {
            short8 kf[2][2];
#pragma unroll
            for (int n2 = 0; n2 < 2; ++n2) {
                const int row = (2 * kc + n2) * 16 + ro;
                const int sw = (row & 7) << 4;
                kf[n2][0] = *(const short8*)(Ks[cur] + row * 128 + (gb ^ sw));
                kf[n2][1] = *(const short8*)(Ks[cur] + row * 128 + ((64 + gb) ^ sw));
            }
#pragma unroll
            for (int mi = 0; mi < 2; ++mi) {
                f32x4 s0 = (f32x4)0.0f, s1 = (f32x4)0.0f;
                s0 = __builtin_amdgcn_mfma_f32_16x16x32_bf16(kf[0][0], qf[mi][0], s0, 0, 0, 0);
                s0 = __builtin_amdgcn_mfma_f32_16x16x32_bf16(kf[0][1], qf[mi][1], s0, 0, 0, 0);
                s1 = __builtin_amdgcn_mfma_f32_16x16x32_bf16(kf[1][0], qf[mi][0], s1, 0, 0, 0);
                s1 = __builtin_amdgcn_mfma_f32_16x16x32_bf16(kf[1][1], qf[mi][1], s1, 0, 0, 0);
                const u64 mv = mi ? mc1 : mc0;
                unsigned pk[4];
#pragma unroll
                for (int n2 = 0; n2 < 2; ++n2) {
                    const f32x4 sv = n2 ? s1 : s0;
                    float p[4];
#pragma unroll
                    for (int j = 0; j < 4; ++j) {
                        // bit index: kcol = 32*kc + 16*n2 + 4*g + j
                        const unsigned u = (unsigned)(mv >> (kc * 32 + g4 + j));
                        const float e = fexp2(sv[j]);
                        p[j] = (u & (n2 ? 0x10000u : 1u)) ? e : 0.f;
                    }
                    asm("v_cvt_pk_bf16_f32 %0, %1, %2" : "=v"(pk[2 * n2])     : "v"(p[0]), "v"(p[1]));
                    asm("v_cvt_pk_bf16_f32 %0, %1, %2" : "=v"(pk[2 * n2 + 1]) : "v"(p[2]), "v"(p[3]));
                }
                union { unsigned u[4]; short8 s; } cc;
                cc.u[0] = pk[0]; cc.u[1] = pk[1]; cc.u[2] = pk[2]; cc.u[3] = pk[3];
                pf[mi][kc] = cc.s;
            }
        }

        // ---- l += P*1 ; O += P V ----
#pragma unroll
        for (int mi = 0; mi < 2; ++mi) {
            lacc[mi] = __builtin_amdgcn_mfma_f32_16x16x32_bf16(pf[mi][0], ones, lacc[mi], 0, 0, 0);
            lacc[mi] = __builtin_amdgcn_mfma_f32_16x16x32_bf16(pf[mi][1], ones, lacc[mi], 0, 0, 0);
        }
#pragma unroll
        for (int dn = 0; dn < 4; ++dn) {
            const int row = dn * 16 + ro;
            const int sw = (row & 7) << 4;
            short8 v0 = *(const short8*)(Vs[cur] + row * 128 + (gb ^ sw));
            short8 v1 = *(const short8*)(Vs[cur] + row * 128 + ((64 + gb) ^ sw));
#pragma unroll
            for (int mi = 0; mi < 2; ++mi) {
                o[mi][dn] = __builtin_amdgcn_mfma_f32_16x16x32_bf16(pf[mi][0], v0, o[mi][dn], 0, 0, 0);
                o[mi][dn] = __builtin_amdgcn_mfma_f32_16x16x32_bf16(pf[mi][1], v1, o[mi][dn], 0, 0, 0);
            }
        }

        __syncthreads();   // drains prefetch; protects buffer reuse
    }

    // ---- normalize + write ctx: lane (g,ro) holds O[qrow=mi*16+4g+j][d=dn*16+ro] ----
#pragma unroll
    for (int mi = 0; mi < 2; ++mi) {
        float inv[4];
#pragma unroll
        for (int j = 0; j < 4; ++j) inv[j] = 1.f / lacc[mi][j];
#pragma unroll
        for (int dn = 0; dn < 4; ++dn)
#pragma unroll
            for (int j = 0; j < 4; ++j) {
                const size_t qr = tokbase + q0 + w * 32 + mi * 16 + g4 + j;
                Ctx[qr * D_MODEL + h * 64 + dn * 16 + ro] = f2bf(o[mi][dn][j] * inv[j]);
            }
    }
}

extern "C" void kernel_launch(void* const* d_in, const int* in_sizes, int n_in,
                              void* d_out, int out_size, void* d_ws, size_t ws_size,
                              hipStream_t stream)
{
    const float* q    = (const float*)d_in[0];
    const float* k    = (const float*)d_in[1];
    const float* v    = (const float*)d_in[2];
    const int*   mask = (const int*)  d_in[3];
    const float* Wq   = (const float*)d_in[4];
    const float* bq   = (const float*)d_in[5];
    const float* Wk   = (const float*)d_in[6];
    const float* bk   = (const float*)d_in[7];
    const float* Wv   = (const float*)d_in[8];
    const float* bv   = (const float*)d_in[9];
    const float* Wo   = (const float*)d_in[10];
    const float* bo   = (const float*)d_in[11];
    float* out = (float*)d_out;

    u16* ws16 = (u16*)d_ws;
    const size_t M1 = 1024 * 1024;
    u16* qb  = ws16;               // 4M elems each
    u16* kb  = ws16 + 4 * M1;
    u16* vb  = ws16 + 8 * M1;
    u16* Wqb = ws16 + 12 * M1;     // 1M each
    u16* Wkb = ws16 + 13 * M1;
    u16* Wvb = ws16 + 14 * M1;
    u16* Wob = ws16 + 15 * M1;
    u16* Qp  = ws16 + 16 * M1;
    u16* Kp  = ws16 + 20 * M1;
    u16* Vt  = ws16 + 24 * M1;     // V^T [D_MODEL][M_ROWS], sigma-permuted per 64-group
    u64* maskb = (u64*)(ws16 + 28 * M1);   // 1 MB
    u16* Ctx = qb;                 // qb dead after gemm_proj

    cvt_and_mask<<<2048, 256, 0, stream>>>(q, k, v, Wq, Wk, Wv, Wo,
                                           qb, kb, vb, Wqb, Wkb, Wvb, Wob,
                                           mask, maskb);

    dim3 gproj(256, 3);
    gemm_proj<<<gproj, 256, 0, stream>>>(qb, kb, vb, Wqb, Wkb, Wvb, bq, bk, bv, Qp, Kp, Vt);

    dim3 ga(SEQ / 128, BATCH * N_HEAD);     // (16, 32) = 512 blocks
    attn_mfma<<<ga, 256, 0, stream>>>(Qp, Kp, Vt, maskb, Ctx);

    dim3 go(D_MODEL / 64, M_ROWS / 128);    // 512 blocks
    gemm_out<<<go, 256, 0, stream>>>(Ctx, Wob, bo, out);
}